// Round 9
// baseline (2790.515 us; speedup 1.0000x reference)
//
#include <hip/hip_runtime.h>
#include <hip/hip_bf16.h>

typedef _Float16 f16;
typedef __attribute__((ext_vector_type(8))) _Float16 f16x8;
typedef __attribute__((ext_vector_type(4))) _Float16 f16x4;
typedef __attribute__((ext_vector_type(4))) float f32x4;

#define DEVI __device__ __forceinline__

DEVI float ldf(const void* p, size_t i, int isf32) {
    if (isf32) return ((const float*)p)[i];
    unsigned int u = ((const unsigned short*)p)[i];
    union { unsigned int b; float f; } c; c.b = u << 16;
    return c.f;
}

DEVI void gld_lds16(const f16* g, f16* l) {
    __builtin_amdgcn_global_load_lds(
        (__attribute__((address_space(1))) void*)(g),
        (__attribute__((address_space(3))) void*)(l), 16, 0, 0);
}

__global__ void detect_dtype(const void* qt, int* flag) {
    if (threadIdx.x == 0 && blockIdx.x == 0) {
        const unsigned int* w = (const unsigned int*)qt;
        int cnt = 0;
        for (int i = 0; i < 64; ++i) {
            unsigned int lo = w[i] & 0xFFFFu;
            union { unsigned int b; float f; } c; c.b = lo << 16;
            if (c.f >= 1e-4f && c.f <= 100.5f) ++cnt;
        }
        *flag = (cnt >= 32) ? 0 : 1;   // 0 = bf16, 1 = fp32
    }
}

__global__ __launch_bounds__(256)
void cvt_in(const void* __restrict__ src, float* __restrict__ dst, int n,
            const int* __restrict__ flag) {
    const int f32 = *flag;
    int i = blockIdx.x * 256 + threadIdx.x;
    if (i < n) dst[i] = ldf(src, i, f32);
}

__global__ __launch_bounds__(256)
void fill_out(float* out, float v) {
    out[blockIdx.x * 256 + threadIdx.x] = v;
}

// =====================================================================
// gemm256: 8-wave 256x256 MFMA GEMM, BK=64, dbuf LDS (128 KB, 1 blk/CU),
// single vmcnt(0)+barrier per 64-MFMA K-iteration (round-6 best for
// FFN1: 150 us). nz-fastest mapping + bijective XCD swizzle.
// Swapped MFMA operands. N = output row stride.
// EPI: 0 = bias->f16 ; 2 = bias+gelu->f16.
// =====================================================================
template<int EPI>
__global__ __launch_bounds__(512, 2)
void gemm256(const f16* __restrict__ Ag, const f16* __restrict__ BTg,
             const float* __restrict__ biasg, void* __restrict__ outg,
             int NZ, int gridN, int N, int K, int lda,
             long zsB, long zsBias, long zsC)
{
    const int tid = threadIdx.x;
    const int w = tid >> 6, lane = tid & 63;
    const int wm = w >> 2, wn = w & 3;
    const int r16 = lane & 15, q4 = lane >> 4;

    const int cpx = gridDim.x >> 3;
    const int id  = (blockIdx.x & 7) * cpx + (blockIdx.x >> 3);

    const int nz   = id % NZ;
    const int mloc = id / NZ;
    const int z    = nz / gridN;
    const int nt   = nz - z * gridN;
    const int tm = mloc * 256, tn = nt * 256;

    const f16*   BT   = BTg + (size_t)z * zsB;
    const float* bias = biasg + (size_t)z * zsBias;
    const size_t zoffC = (size_t)z * zsC;

    __shared__ __align__(16) f16 smA[2][2][16][64][8];   // 64 KB
    __shared__ __align__(16) f16 smB[2][2][16][64][8];   // 64 KB

    const f16* gA[4]; const f16* gB[4];
#pragma unroll
    for (int t = 0; t < 4; ++t) {
        const int c = 4 * w + t, kk = c >> 4, rc = c & 15;
        gA[t] = Ag + (size_t)(tm + rc * 16 + r16) * lda + kk * 32 + q4 * 8;
        gB[t] = BT + (size_t)(tn + rc * 16 + r16) * K  + kk * 32 + q4 * 8;
    }
    f16* const smAbase = &smA[0][0][0][0][0];
    f16* const smBbase = &smB[0][0][0][0][0];
    const int coff = (4 * w) * 512;

    auto issue = [&](int kt, int buf) {
        const size_t o = (size_t)kt * 64;
        const int bo = buf * 16384 + coff;
#pragma unroll
        for (int t = 0; t < 4; ++t) {
            gld_lds16(gA[t] + o, smAbase + bo + t * 512);
            gld_lds16(gB[t] + o, smBbase + bo + t * 512);
        }
    };

    f32x4 acc[8][4];
#pragma unroll
    for (int i = 0; i < 8; ++i)
#pragma unroll
        for (int j = 0; j < 4; ++j) acc[i][j] = (f32x4)0.0f;

    const int iters = K >> 6;                   // BK = 64
    issue(0, 0);
    __builtin_amdgcn_s_waitcnt(0x0F70);         // vmcnt(0)
    __builtin_amdgcn_s_barrier();
    __asm__ __volatile__("" ::: "memory");

    for (int kt = 0; kt < iters; ++kt) {
        const int cur = kt & 1;
        const bool more = (kt + 1 < iters);
        if (more) issue(kt + 1, cur ^ 1);
#pragma unroll
        for (int kk = 0; kk < 2; ++kk) {
            f16x8 af[8], bf[4];
#pragma unroll
            for (int i = 0; i < 8; ++i)
                af[i] = *(const f16x8*)&smA[cur][kk][wm * 8 + i][lane][0];
#pragma unroll
            for (int j = 0; j < 4; ++j)
                bf[j] = *(const f16x8*)&smB[cur][kk][wn * 4 + j][lane][0];
            // swapped operands: acc[i][j] = C[m = i*16 + r16]
            //                                [n = j*16 + q4*4 + r]
#pragma unroll
            for (int i = 0; i < 8; ++i)
#pragma unroll
                for (int j = 0; j < 4; ++j)
                    acc[i][j] = __builtin_amdgcn_mfma_f32_16x16x32_f16(
                        bf[j], af[i], acc[i][j], 0, 0, 0);
        }
        if (more) {
            __builtin_amdgcn_s_waitcnt(0x0F70);
            __builtin_amdgcn_s_barrier();
            __asm__ __volatile__("" ::: "memory");
        }
    }

    const int rowBase = tm + wm * 128;
    const int colBase = tn + wn * 64;
#pragma unroll
    for (int i = 0; i < 8; ++i) {
        const int row = rowBase + i * 16 + r16;
        const size_t rowoff = (size_t)row * N;
#pragma unroll
        for (int j = 0; j < 4; ++j) {
            const int n0 = colBase + j * 16 + q4 * 4;
            const f32x4 bv4 = *(const f32x4*)&bias[n0];
            f16x4 o;
#pragma unroll
            for (int r = 0; r < 4; ++r) {
                float v = acc[i][j][r] + bv4[r];
                if constexpr (EPI == 2) {
                    // gelu_tanh(v) = v - v * rcp(exp(K*t)+1)
                    float v2 = v * v;
                    float t  = v * (1.0f + 0.044715f * v2);
                    float e  = __expf(1.5957691216057308f * t);
                    float rc = __builtin_amdgcn_rcpf(e + 1.0f);
                    v = v - v * rc;
                }
                o[r] = (f16)v;
            }
            *(f16x4*)((f16*)outg + zoffC + rowoff + n0) = o;
        }
    }
}

// =====================================================================
// gemm_qkv: NEW — gemm_ln's structure minus residual/LN (the structure
// that yields our best inferred GEMM rate on FFN2). 8-wave 128x512
// block; per iter stage A chunk + 4 B chunks (5 gloads/wave), counted
// vmcnt(5); bias->f16 epilogue to z-slab output. id%NZ = z so sibling
// blocks (same XCD) share the A m-tile in L2; B panels (3x512KB)
// L2-resident. grid = 3*M/128 (must be %8==0).
// =====================================================================
__global__ __launch_bounds__(512, 2)
void gemm_qkv(const f16* __restrict__ Ag, const f16* __restrict__ BTg,
              const float* __restrict__ biasg, f16* __restrict__ outg,
              int NZ, int K, int lda, long zsB, long zsBias, long zsC)
{
    const int tid = threadIdx.x;
    const int w = tid >> 6, lane = tid & 63;
    const int wm = w >> 2, wn = w & 3;
    const int r16 = lane & 15, q4 = lane >> 4;

    const int cpx = gridDim.x >> 3;
    const int id  = (blockIdx.x & 7) * cpx + (blockIdx.x >> 3);
    const int z    = id % NZ;
    const int mloc = id / NZ;
    const int tm   = mloc * 128;

    const f16*   BT   = BTg + (size_t)z * zsB;
    const float* bias = biasg + (size_t)z * zsBias;
    f16*         out  = outg + (size_t)z * zsC;

    __shared__ __align__(16) f16 smA[2][8][64][8];    // 16 KB
    __shared__ __align__(16) f16 smB[2][32][64][8];   // 64 KB

    f32x4 acc[4][8];
#pragma unroll
    for (int i = 0; i < 4; ++i)
#pragma unroll
        for (int j = 0; j < 8; ++j) acc[i][j] = (f32x4)0.0f;

    const f16* gA  = Ag + (size_t)(tm + w * 16 + r16) * lda + q4 * 8;
    const f16* gB  = BT + (size_t)(w * 64 + r16) * K + q4 * 8;
    const int iters = K >> 5;

    auto issue = [&](int kt, int buf) {
        const size_t o = (size_t)kt * 32;
        gld_lds16(gA + o, &smA[buf][w][0][0]);
#pragma unroll
        for (int t = 0; t < 4; ++t)
            gld_lds16(gB + (size_t)(t * 16) * K + o, &smB[buf][w * 4 + t][0][0]);
    };

    issue(0, 0);
    for (int kt = 0; kt < iters; ++kt) {
        const int cur = kt & 1;
        __builtin_amdgcn_s_barrier();
        if (kt + 1 < iters) {
            issue(kt + 1, cur ^ 1);
            __builtin_amdgcn_s_waitcnt(0x0F75);  // vmcnt(5)
        } else {
            __builtin_amdgcn_s_waitcnt(0x0F70);  // vmcnt(0)
        }
        __builtin_amdgcn_s_barrier();
        __asm__ __volatile__("" ::: "memory");

        f16x8 af[4], bf[8];
#pragma unroll
        for (int i = 0; i < 4; ++i)
            af[i] = *(const f16x8*)&smA[cur][wm * 4 + i][lane][0];
#pragma unroll
        for (int j = 0; j < 8; ++j)
            bf[j] = *(const f16x8*)&smB[cur][wn * 8 + j][lane][0];
#pragma unroll
        for (int i = 0; i < 4; ++i)
#pragma unroll
            for (int j = 0; j < 8; ++j)
                acc[i][j] = __builtin_amdgcn_mfma_f32_16x16x32_f16(
                    bf[j], af[i], acc[i][j], 0, 0, 0);
    }

    const int rowB = wm * 64;
    const int colB = wn * 128;
#pragma unroll
    for (int i = 0; i < 4; ++i) {
        const int row = tm + rowB + i * 16 + r16;
        const size_t rowoff = (size_t)row * 512;
#pragma unroll
        for (int j = 0; j < 8; ++j) {
            const int n0 = colB + j * 16 + q4 * 4;
            const f32x4 bv4 = *(const f32x4*)&bias[n0];
            f16x4 o;
#pragma unroll
            for (int r = 0; r < 4; ++r) o[r] = (f16)(acc[i][j][r] + bv4[r]);
            *(f16x4*)&out[rowoff + n0] = o;
        }
    }
}

// =====================================================================
// gemm_bt2: 4-wave 128x128 kernel (compress GEMM only, EPI=3 -> f32)
// =====================================================================
template<int EPI>
__global__ __launch_bounds__(256, 4)
void gemm_bt2(const f16* __restrict__ Ag, const f16* __restrict__ BTg,
              const float* __restrict__ biasg, void* __restrict__ outg,
              int NZ, int gridN, int N, int K, int lda,
              long zsB, long zsBias, long zsC)
{
    const int tid  = threadIdx.x;
    const int w    = tid >> 6, lane = tid & 63;
    const int wm   = w >> 1,   wn   = w & 1;
    const int r16  = lane & 15, q4 = lane >> 4;

    const int cpx = gridDim.x >> 3;
    const int id  = (gridDim.x >= 8) ? ((blockIdx.x & 7) * cpx + (blockIdx.x >> 3))
                                     : blockIdx.x;

    const int nz   = id % NZ;
    const int mloc = id / NZ;
    const int z    = nz / gridN;
    const int nt   = nz - z * gridN;
    const int tm   = mloc * 128, tn = nt * 128;

    const f16*   BT   = BTg + (size_t)z * zsB;
    const float* bias = biasg + (size_t)z * zsBias;
    const size_t zoffC = (size_t)z * zsC;

    __shared__ __align__(16) f16 smA[2][8][64][8];
    __shared__ __align__(16) f16 smB[2][8][64][8];

    const int iters = K >> 5;

    const f16* gA0 = Ag + (size_t)(tm + (2 * w) * 16 + r16) * lda + q4 * 8;
    const f16* gA1 = gA0 + (size_t)16 * lda;
    const f16* gB0 = BT + (size_t)(tn + (2 * w) * 16 + r16) * K + q4 * 8;
    const f16* gB1 = gB0 + (size_t)16 * K;

    auto issue = [&](int kt, int buf) {
        const size_t o = (size_t)kt * 32;
        gld_lds16(gA0 + o, &smA[buf][2 * w][0][0]);
        gld_lds16(gA1 + o, &smA[buf][2 * w + 1][0][0]);
        gld_lds16(gB0 + o, &smB[buf][2 * w][0][0]);
        gld_lds16(gB1 + o, &smB[buf][2 * w + 1][0][0]);
    };

    f32x4 acc[4][4];
#pragma unroll
    for (int i = 0; i < 4; ++i)
#pragma unroll
        for (int j = 0; j < 4; ++j) acc[i][j] = (f32x4)0.0f;

    issue(0, 0);
    for (int kt = 0; kt < iters; ++kt) {
        const int cur = kt & 1;
        __builtin_amdgcn_s_barrier();
        if (kt + 1 < iters) {
            issue(kt + 1, cur ^ 1);
            __builtin_amdgcn_s_waitcnt(0x0F74);  // vmcnt(4)
        } else {
            __builtin_amdgcn_s_waitcnt(0x0F70);  // vmcnt(0)
        }
        __builtin_amdgcn_s_barrier();
        __asm__ __volatile__("" ::: "memory");

        f16x8 af[4], bf[4];
#pragma unroll
        for (int i = 0; i < 4; ++i) {
            af[i] = *(const f16x8*)&smA[cur][wm * 4 + i][lane][0];
            bf[i] = *(const f16x8*)&smB[cur][wn * 4 + i][lane][0];
        }
#pragma unroll
        for (int i = 0; i < 4; ++i)
#pragma unroll
            for (int j = 0; j < 4; ++j)
                acc[i][j] = __builtin_amdgcn_mfma_f32_16x16x32_f16(
                    bf[j], af[i], acc[i][j], 0, 0, 0);
    }

    const int rowBase = tm + wm * 64;
    const int colBase = tn + wn * 64;
#pragma unroll
    for (int i = 0; i < 4; ++i) {
        const int row = rowBase + i * 16 + r16;
        const size_t rowoff = (size_t)row * N;
#pragma unroll
        for (int j = 0; j < 4; ++j) {
            const int n0 = colBase + j * 16 + q4 * 4;
            const f32x4 bv4 = *(const f32x4*)&bias[n0];
            if constexpr (EPI == 3) {
                f32x4 o;
#pragma unroll
                for (int r = 0; r < 4; ++r) o[r] = acc[i][j][r] + bv4[r];
                *(f32x4*)((float*)outg + rowoff + n0) = o;
            } else {
                f16x4 o;
#pragma unroll
                for (int r = 0; r < 4; ++r) o[r] = (f16)(acc[i][j][r] + bv4[r]);
                *(f16x4*)((f16*)outg + zoffC + rowoff + n0) = o;
            }
        }
    }
}

// =====================================================================
// gemm_ln: 8-wave 128x512 fused GEMM + bias + residual + LayerNorm.
// lda: A row stride; rstride: residual row stride; output compact 512.
// =====================================================================
__global__ __launch_bounds__(512, 2)
void gemm_ln(const f16* __restrict__ Ag, const f16* __restrict__ BTg,
             const float* __restrict__ bias, const f16* __restrict__ resg,
             const float* __restrict__ lng, const float* __restrict__ lnb,
             f16* __restrict__ Yg, int K, int lda, int rstride)
{
    const int tid = threadIdx.x;
    const int w = tid >> 6, lane = tid & 63;
    const int wm = w >> 2, wn = w & 3;
    const int r16 = lane & 15, q4 = lane >> 4;
    const int tm = blockIdx.x * 128;

    __shared__ __align__(16) f16 smA[2][8][64][8];    // 16 KB
    __shared__ __align__(16) f16 smB[2][32][64][8];   // 64 KB
    __shared__ __align__(16) float lnS[128][4];
    __shared__ __align__(16) float lnQ[128][4];

    f32x4 acc[4][8];
#pragma unroll
    for (int i = 0; i < 4; ++i)
#pragma unroll
        for (int j = 0; j < 8; ++j) acc[i][j] = (f32x4)0.0f;

    const f16* gA  = Ag  + (size_t)(tm + w * 16 + r16) * lda + q4 * 8;
    const f16* gB  = BTg + (size_t)(w * 64 + r16) * K + q4 * 8;
    const int iters = K >> 5;

    auto issue = [&](int kt, int buf) {
        const size_t o = (size_t)kt * 32;
        gld_lds16(gA + o, &smA[buf][w][0][0]);
#pragma unroll
        for (int t = 0; t < 4; ++t)
            gld_lds16(gB + (size_t)(t * 16) * K + o, &smB[buf][w * 4 + t][0][0]);
    };

    issue(0, 0);
    for (int kt = 0; kt < iters; ++kt) {
        const int cur = kt & 1;
        __builtin_amdgcn_s_barrier();
        if (kt + 1 < iters) {
            issue(kt + 1, cur ^ 1);
            __builtin_amdgcn_s_waitcnt(0x0F75);  // vmcnt(5)
        } else {
            __builtin_amdgcn_s_waitcnt(0x0F70);  // vmcnt(0)
        }
        __builtin_amdgcn_s_barrier();
        __asm__ __volatile__("" ::: "memory");

        f16x8 af[4], bf[8];
#pragma unroll
        for (int i = 0; i < 4; ++i)
            af[i] = *(const f16x8*)&smA[cur][wm * 4 + i][lane][0];
#pragma unroll
        for (int j = 0; j < 8; ++j)
            bf[j] = *(const f16x8*)&smB[cur][wn * 8 + j][lane][0];
#pragma unroll
        for (int i = 0; i < 4; ++i)
#pragma unroll
            for (int j = 0; j < 8; ++j)
                acc[i][j] = __builtin_amdgcn_mfma_f32_16x16x32_f16(
                    bf[j], af[i], acc[i][j], 0, 0, 0);
    }

    const int rowB = wm * 64;
    const int colB = wn * 128;

    float ps[4], pq[4];
#pragma unroll
    for (int i = 0; i < 4; ++i) {
        const int grow = tm + rowB + i * 16 + r16;
        const size_t roff = (size_t)grow * rstride;
        float s = 0.f, sq = 0.f;
#pragma unroll
        for (int j = 0; j < 8; ++j) {
            const int n0 = colB + j * 16 + q4 * 4;
            const f32x4 biv = *(const f32x4*)&bias[n0];
            const f16x4 rv  = *(const f16x4*)&resg[roff + n0];
#pragma unroll
            for (int r = 0; r < 4; ++r) {
                float v = acc[i][j][r] + biv[r] + (float)rv[r];
                acc[i][j][r] = v;
                s += v; sq += v * v;
            }
        }
        s  += __shfl_xor(s, 16, 64);  s  += __shfl_xor(s, 32, 64);
        sq += __shfl_xor(sq, 16, 64); sq += __shfl_xor(sq, 32, 64);
        ps[i] = s; pq[i] = sq;
    }
    if (q4 == 0) {
#pragma unroll
        for (int i = 0; i < 4; ++i) {
            const int lr = rowB + i * 16 + r16;
            lnS[lr][wn] = ps[i];
            lnQ[lr][wn] = pq[i];
        }
    }
    __syncthreads();

#pragma unroll
    for (int i = 0; i < 4; ++i) {
        const int lr = rowB + i * 16 + r16;
        const f32x4 s4 = *(const f32x4*)&lnS[lr][0];
        const f32x4 q4v = *(const f32x4*)&lnQ[lr][0];
        const float s  = s4[0] + s4[1] + s4[2] + s4[3];
        const float sq = q4v[0] + q4v[1] + q4v[2] + q4v[3];
        const float mu = s * (1.0f / 512.0f);
        const float var = sq * (1.0f / 512.0f) - mu * mu;
        const float rs = rsqrtf(var + 1e-5f);
        const size_t rowoff = (size_t)(tm + lr) * 512;
#pragma unroll
        for (int j = 0; j < 8; ++j) {
            const int n0 = colB + j * 16 + q4 * 4;
            const f32x4 g4 = *(const f32x4*)&lng[n0];
            const f32x4 b4 = *(const f32x4*)&lnb[n0];
            f16x4 o;
#pragma unroll
            for (int r = 0; r < 4; ++r)
                o[r] = (f16)(g4[r] * (acc[i][j][r] - mu) * rs + b4[r]);
            *(f16x4*)&Yg[rowoff + n0] = o;
        }
    }
}

// =====================================================================
// Attention: mode 0 = full (16384 slabs); mode 1 = layer-0 dedup input.
// =====================================================================
__global__ __launch_bounds__(256)
void attn_kernel(const f16* __restrict__ qg, const f16* __restrict__ kg,
                 const f16* __restrict__ vg, const float* __restrict__ biasL,
                 f16* __restrict__ cg, int mode)
{
    const int w = threadIdx.x >> 6, lane = threadIdx.x & 63;
    const int j = blockIdx.x * 4 + w;
    __shared__ __align__(16) f16 sQ[4][8][136];
    __shared__ __align__(16) f16 sK[4][8][136];
    __shared__ __align__(16) f16 sV[4][8][136];
    __shared__ float sP[4][8][8];

    const size_t base  = (size_t)j * 1024;
    const size_t ibase = (mode == 1)
        ? ((size_t)(j >> 7) * 4096 + (size_t)(j & 3) * 1024) : base;
#pragma unroll
    for (int t = 0; t < 2; ++t) {
        int flat = (t * 64 + lane) * 8;
        int r = flat >> 7, c = flat & 127;
        *(f16x8*)&sQ[w][r][c] = *(const f16x8*)(qg + ibase + flat);
        *(f16x8*)&sK[w][r][c] = *(const f16x8*)(kg + ibase + flat);
        *(f16x8*)&sV[w][r][c] = *(const f16x8*)(vg + ibase + flat);
    }
    __syncthreads();

    const int i = lane >> 3, jj = lane & 7;
    float d = 0.f;
#pragma unroll
    for (int c = 0; c < 16; ++c) {
        f16x8 qv = *(const f16x8*)&sQ[w][i][c * 8];
        f16x8 kv = *(const f16x8*)&sK[w][jj][c * 8];
#pragma unroll
        for (int e = 0; e < 8; ++e) d += (float)qv[e] * (float)kv[e];
    }
    float s = d * 0.17677669529663687f + biasL[(size_t)(j & 4095) * 64 + lane];
    float mx = s;
    mx = fmaxf(mx, __shfl_xor(mx, 1, 64));
    mx = fmaxf(mx, __shfl_xor(mx, 2, 64));
    mx = fmaxf(mx, __shfl_xor(mx, 4, 64));
    float p = __expf(s - mx);
    float sum = p;
    sum += __shfl_xor(sum, 1, 64);
    sum += __shfl_xor(sum, 2, 64);
    sum += __shfl_xor(sum, 4, 64);
    sP[w][i][jj] = p / sum;
    __syncthreads();

#pragma unroll
    for (int t2 = 0; t2 < 8; ++t2) {
        float ap[8];
#pragma unroll
        for (int e = 0; e < 8; ++e) ap[e] = sP[w][t2][e];
#pragma unroll
        for (int h = 0; h < 2; ++h) {
            int flat = (t2 * 2 + h) * 64 + lane;
            int dd = flat & 127;
            float o = 0.f;
#pragma unroll
            for (int e = 0; e < 8; ++e) o += ap[e] * (float)sV[w][e][dd];
            cg[base + flat] = (f16)o;
        }
    }
}

// =====================================================================
// x0 builders / preamble kernels
// =====================================================================
__global__ __launch_bounds__(256)
void build_x0(const void* __restrict__ sup, const void* __restrict__ cls,
              f16* __restrict__ xb, const int* __restrict__ flag)
{
    const int f32 = *flag;
    const size_t idx = ((size_t)blockIdx.x * 256 + threadIdx.x) * 4;
    const int row = (int)(idx >> 9), col0 = (int)(idx & 511);
    const int s = row & 7, b = row >> 8;
    f16x4 o;
#pragma unroll
    for (int e = 0; e < 4; ++e) {
        const int md = (col0 + e) & 127;
        float v = (s == 0) ? ldf(cls, md, f32)
                           : ldf(sup, ((size_t)b * 7 + (s - 1)) * 128 + md, f32);
        o[e] = (f16)v;
    }
    *(f16x4*)(xb + idx) = o;
}

__global__ __launch_bounds__(256)
void build_x0s(const void* __restrict__ sup, const void* __restrict__ cls,
               f16* __restrict__ xs, const int* __restrict__ flag)
{
    const int f32 = *flag;
    const size_t idx = ((size_t)blockIdx.x * 256 + threadIdx.x) * 4;
    const int row = (int)(idx >> 9), col0 = (int)(idx & 511);
    const int s = row & 7, b = row >> 3;
    f16x4 o;
#pragma unroll
    for (int e = 0; e < 4; ++e) {
        const int md = (col0 + e) & 127;
        float v = (s == 0) ? ldf(cls, md, f32)
                           : ldf(sup, ((size_t)b * 7 + (s - 1)) * 128 + md, f32);
        o[e] = (f16)v;
    }
    *(f16x4*)(xs + idx) = o;
}

__global__ __launch_bounds__(256)
void bias_kernel(const void* __restrict__ qt, const void* __restrict__ st,
                 const void* __restrict__ freq, const void* __restrict__ phase,
                 const void* __restrict__ tw, float* __restrict__ biasAll,
                 const int* __restrict__ flag)
{
    const int f32 = *flag;
    const int lane = threadIdx.x & 63;
    const int bq = blockIdx.x * 4 + (threadIdx.x >> 6);
    const int b = bq >> 5, qq = bq & 31;
    const int i = lane >> 3, jj = lane & 7;
    const float ti = (i  == 0) ? ldf(qt, b * 32 + qq, f32) : ldf(st, b * 7 + i  - 1, f32);
    const float tj = (jj == 0) ? ldf(qt, b * 32 + qq, f32) : ldf(st, b * 7 + jj - 1, f32);
    const float td = ti - tj;
    float a[6] = {0.f, 0.f, 0.f, 0.f, 0.f, 0.f};
    for (int t = 0; t < 32; ++t) {
        float c = __cosf(td * ldf(freq, t, f32) + ldf(phase, t, f32));
#pragma unroll
        for (int l = 0; l < 6; ++l) a[l] += c * ldf(tw, l * 32 + t, f32);
    }
#pragma unroll
    for (int l = 0; l < 6; ++l)
        biasAll[(size_t)l * (4096 * 64) + (size_t)bq * 64 + lane] = a[l];
}

__global__ __launch_bounds__(256)
void transpose_cvt(const void* __restrict__ W, f16* __restrict__ WT,
                   int K, int N, long zsW, long zsWT, const int* __restrict__ flag)
{
    const int f32 = *flag;
    const size_t zoff = (size_t)blockIdx.z * zsW;
    f16* WTz = WT + (size_t)blockIdx.z * zsWT;
    __shared__ float tile[64][65];
    const int tn = blockIdx.x * 64, tk = blockIdx.y * 64;
#pragma unroll
    for (int t = 0; t < 16; ++t) {
        int idx = t * 256 + threadIdx.x;
        int r = idx >> 6, c = idx & 63;
        tile[r][c] = ldf(W, zoff + (size_t)(tk + r) * N + tn + c, f32);
    }
    __syncthreads();
#pragma unroll
    for (int t = 0; t < 16; ++t) {
        int idx = t * 256 + threadIdx.x;
        int r = idx >> 6, c = idx & 63;
        WTz[(size_t)(tn + r) * K + tk + c] = (f16)tile[c][r];
    }
}

__global__ __launch_bounds__(256)
void gather_qkvb(const void* __restrict__ bq, const void* __restrict__ bk,
                 const void* __restrict__ bv, float* __restrict__ dst,
                 const int* __restrict__ flag)
{
    const int f32 = *flag;
    int i = blockIdx.x * 256 + threadIdx.x;
    if (i < 9216) {
        int z = i / 3072, rem = i % 3072;
        const void* src = (z == 0) ? bq : ((z == 1) ? bk : bv);
        dst[i] = ldf(src, rem, f32);
    }
}

__global__ __launch_bounds__(256)
void bn_reduce(const float* __restrict__ h0, float* __restrict__ stats)
{
    const int t = blockIdx.x * 256 + threadIdx.x;
    float s = 0.f, ss = 0.f;
#pragma unroll
    for (int k = 0; k < 8; ++k) {
        float v = h0[t + k * 65536];
        s += v; ss += v * v;
    }
#pragma unroll
    for (int m = 1; m <= 32; m <<= 1) {
        s  += __shfl_xor(s, m, 64);
        ss += __shfl_xor(ss, m, 64);
    }
    __shared__ float ls[8];
    const int w = threadIdx.x >> 6, lane = threadIdx.x & 63;
    if (lane == 0) { ls[w] = s; ls[4 + w] = ss; }
    __syncthreads();
    if (threadIdx.x == 0) {
        atomicAdd(&stats[0], ls[0] + ls[1] + ls[2] + ls[3]);
        atomicAdd(&stats[1], ls[4] + ls[5] + ls[6] + ls[7]);
    }
}

__global__ __launch_bounds__(256)
void bn_apply(const float* __restrict__ h0, const float* __restrict__ stats,
              const float* __restrict__ bnp, float* __restrict__ out)
{
    const int t = blockIdx.x * 256 + threadIdx.x;
    const float mu  = stats[0] * (1.0f / 524288.0f);
    const float var = stats[1] * (1.0f / 524288.0f) - mu * mu;
    const float rs  = rsqrtf(var + 1e-5f);
    float v = bnp[0] * (h0[t] - mu) * rs + bnp[8];
    v = (v >= 0.f) ? v : 0.01f * v;
    out[t] = v;
}

// =====================================================================
extern "C" void kernel_launch(void* const* d_in, const int* in_sizes, int n_in,
                              void* d_out, int out_size, void* d_ws, size_t ws_size,
                              hipStream_t stream)
{
    (void)in_sizes; (void)n_in; (void)out_size;
    const void* sup   = d_in[0];
    const void* qt    = d_in[1];
    const void* st    = d_in[2];
    const void* cls   = d_in[3];
    const void* freq  = d_in[4];
    const void* phase = d_in[5];
    const void* Wq = d_in[6];  const void* bqv = d_in[7];
    const void* Wk = d_in[8];  const void* bkv = d_in[9];
    const void* Wv = d_in[10]; const void* bvv = d_in[11];
    const void* Wo = d_in[12]; const void* bo  = d_in[13];
    const void* ln1g = d_in[14]; const void* ln1b = d_in[15];
    const void* tw = d_in[16];
    const void* W1 = d_in[17]; const void* b1 = d_in[18];
    const void* W2 = d_in[19]; const void* b2 = d_in[20];
    const void* ln2g = d_in[21]; const void* ln2b = d_in[22];
    const void* Wc = d_in[23]; const void* bc = d_in[24];
    const void* bng = d_in[25]; const void* bnb = d_in[26];

    const size_t NEEDED = 245658240;
    if (ws_size < NEEDED) {
        fill_out<<<2048, 256, 0, stream>>>((float*)d_out, 999.0f);
        return;
    }

    char* ws = (char*)d_ws;
    f16*   wt      = (f16*)(ws + 0);
    float* biasAll = (float*)(ws + 37879808);
    float* qkvb    = (float*)(ws + 44171264);
    float* prm     = (float*)(ws + 44208128);
    float* stats   = (float*)(ws + 44331584);
    int*   flag    = (int*)  (ws + 44331592);
    f16*   xb      = (f16*)(ws + 44331648);
    f16*   ob      = (f16*)(ws + 77886080);
    char*  region  = ws + 111440512;
    f16*   qb      = (f16*)(region);
    f16*   kb      = (f16*)(region + 33554432);
    f16*   vb      = (f16*)(region + 67108864);
    f16*   cb      = (f16*)(region + 100663296);
    f16*   qs      = (f16*)(region);
    f16*   xs      = (f16*)(region + 100663296);
    f16*   fbuf    = (f16*)(region);
    float* h0      = (float*)(region);

    detect_dtype<<<1, 64, 0, stream>>>(qt, flag);

    cvt_in<<<12, 256, 0, stream>>>(bo,   prm + 0,     3072,  flag);
    cvt_in<<<48, 256, 0, stream>>>(b1,   prm + 3072,  12288, flag);
    cvt_in<<<12, 256, 0, stream>>>(b2,   prm + 15360, 3072,  flag);
    cvt_in<<<1,  256, 0, stream>>>(bc,   prm + 18432, 128,   flag);
    cvt_in<<<12, 256, 0, stream>>>(ln1g, prm + 18560, 3072,  flag);
    cvt_in<<<12, 256, 0, stream>>>(ln1b, prm + 21632, 3072,  flag);
    cvt_in<<<12, 256, 0, stream>>>(ln2g, prm + 24704, 3072,  flag);
    cvt_in<<<12, 256, 0, stream>>>(ln2b, prm + 27776, 3072,  flag);
    cvt_in<<<1,  256, 0, stream>>>(bng,  prm + 30848, 8,     flag);
    cvt_in<<<1,  256, 0, stream>>>(bnb,  prm + 30856, 8,     flag);

    transpose_cvt<<<dim3(8, 8, 6),  256, 0, stream>>>(Wq, wt + 0,        512, 512,  262144, 262144, flag);
    transpose_cvt<<<dim3(8, 8, 6),  256, 0, stream>>>(Wk, wt + 1572864,  512, 512,  262144, 262144, flag);
    transpose_cvt<<<dim3(8, 8, 6),  256, 0, stream>>>(Wv, wt + 3145728,  512, 512,  262144, 262144, flag);
    transpose_cvt<<<dim3(8, 8, 6),  256, 0, stream>>>(Wo, wt + 4718592,  512, 512,  262144, 262144, flag);
    transpose_cvt<<<dim3(32, 8, 6), 256, 0, stream>>>(W1, wt + 6291456,  512, 2048, 1048576, 1048576, flag);
    transpose_cvt<<<dim3(8, 32, 6), 256, 0, stream>>>(W2, wt + 12582912, 2048, 512, 1048576, 1048576, flag);
    transpose_cvt<<<dim3(2, 8, 1),  256, 0, stream>>>(Wc, wt + 18874368, 512, 128,  0, 0, flag);
    gather_qkvb<<<36, 256, 0, stream>>>(bqv, bkv, bvv, qkvb, flag);
    build_x0<<<16384, 256, 0, stream>>>(sup, cls, xb, flag);
    build_x0s<<<512, 256, 0, stream>>>(sup, cls, xs, flag);
    bias_kernel<<<1024, 256, 0, stream>>>(qt, st, freq, phase, tw, biasAll, flag);
    hipMemsetAsync(stats, 0, 8, stream);

    for (int l = 0; l < 6; ++l) {
        if (l == 0) {
            // QKV on deduped x0: M=1024, gemm256 (24 blocks)
            gemm256<0><<<24, 512, 0, stream>>>(
                xs, wt, qkvb, qs,
                6, 2, 512, 512, 512, 1572864, 3072, 524288);
            attn_kernel<<<4096, 256, 0, stream>>>(
                qs, qs + 524288, qs + 1048576, biasAll, cb, 1);
        } else {
            // QKV via gemm_ln-structure kernel: 256 m-tiles x 3 z = 768
            gemm_qkv<<<768, 512, 0, stream>>>(
                xb, wt + l * 262144, qkvb + l * 512, qb,
                3, 512, 512, 1572864, 3072, 16777216);
            attn_kernel<<<4096, 256, 0, stream>>>(
                qb, kb, vb, biasAll + (size_t)l * 262144, cb, 0);
        }
        // O-proj + bias + residual(xb) + LN1 -> ob  (fused)
        gemm_ln<<<256, 512, 0, stream>>>(
            cb, wt + 4718592 + l * 262144, prm + 0 + l * 512, xb,
            prm + 18560 + l * 512, prm + 21632 + l * 512, ob, 512, 512, 512);
        if (l < 5) {
            // FFN1 + gelu -> fbuf : 128 m x 8 n = 1024 blocks
            gemm256<2><<<1024, 512, 0, stream>>>(
                ob, wt + 6291456 + l * 1048576, prm + 3072 + l * 2048, fbuf,
                8, 8, 2048, 512, 512, 0, 0, 0);
            // FFN2 + bias + residual(ob) + LN2 -> xb
            gemm_ln<<<256, 512, 0, stream>>>(
                fbuf, wt + 12582912 + l * 1048576, prm + 15360 + l * 512, ob,
                prm + 24704 + l * 512, prm + 27776 + l * 512, xb, 2048, 2048, 512);
        } else {
            // Last layer: only s==0 rows feed compress. M = 4096.
            // FFN1 on strided rows of ob (row r -> ob row 8r, lda=4096)
            gemm256<2><<<128, 512, 0, stream>>>(
                ob, wt + 6291456 + l * 1048576, prm + 3072 + l * 2048, fbuf,
                8, 8, 2048, 512, 4096, 0, 0, 0);
            // FFN2 + residual(ob strided) + LN2 -> cb compact [4096,512]
            gemm_ln<<<32, 512, 0, stream>>>(
                fbuf, wt + 12582912 + l * 1048576, prm + 15360 + l * 512, ob,
                prm + 24704 + l * 512, prm + 27776 + l * 512, cb, 2048, 2048, 4096);
        }
    }

    // compress on compact [4096,512] CLS rows
    gemm_bt2<3><<<32, 256, 0, stream>>>(
        cb, wt + 18874368, prm + 18432, h0,
        1, 1, 128, 512, 512, 0, 0, 0);
    bn_reduce<<<256, 256, 0, stream>>>(h0, stats);
    bn_apply<<<2048, 256, 0, stream>>>(h0, stats, prm + 30848, (float*)d_out);
}

// Round 12
// 2721.124 us; speedup vs baseline: 1.0255x; 1.0255x over previous
//
#include <hip/hip_runtime.h>
#include <hip/hip_bf16.h>

typedef _Float16 f16;
typedef __attribute__((ext_vector_type(8))) _Float16 f16x8;
typedef __attribute__((ext_vector_type(4))) _Float16 f16x4;
typedef __attribute__((ext_vector_type(4))) float f32x4;

#define DEVI __device__ __forceinline__

DEVI float ldf(const void* p, size_t i, int isf32) {
    if (isf32) return ((const float*)p)[i];
    unsigned int u = ((const unsigned short*)p)[i];
    union { unsigned int b; float f; } c; c.b = u << 16;
    return c.f;
}

DEVI void gld_lds16(const f16* g, f16* l) {
    __builtin_amdgcn_global_load_lds(
        (__attribute__((address_space(1))) void*)(g),
        (__attribute__((address_space(3))) void*)(l), 16, 0, 0);
}

__global__ void detect_dtype(const void* qt, int* flag) {
    if (threadIdx.x == 0 && blockIdx.x == 0) {
        const unsigned int* w = (const unsigned int*)qt;
        int cnt = 0;
        for (int i = 0; i < 64; ++i) {
            unsigned int lo = w[i] & 0xFFFFu;
            union { unsigned int b; float f; } c; c.b = lo << 16;
            if (c.f >= 1e-4f && c.f <= 100.5f) ++cnt;
        }
        *flag = (cnt >= 32) ? 0 : 1;   // 0 = bf16, 1 = fp32
    }
}

__global__ __launch_bounds__(256)
void cvt_in(const void* __restrict__ src, float* __restrict__ dst, int n,
            const int* __restrict__ flag) {
    const int f32 = *flag;
    int i = blockIdx.x * 256 + threadIdx.x;
    if (i < n) dst[i] = ldf(src, i, f32);
}

__global__ __launch_bounds__(256)
void fill_out(float* out, float v) {
    out[blockIdx.x * 256 + threadIdx.x] = v;
}

// =====================================================================
// gemm256: 8-wave 256x256 MFMA GEMM, BK=64, dbuf LDS (128 KB, 1 blk/CU),
// single vmcnt(0)+barrier per 64-MFMA K-iteration. STABLE schedule
// (passed rounds 2/3/8/9; perf == phased variant: FFN1 152.9 vs 150.3).
// nz-fastest mapping + bijective XCD swizzle (FETCH 135->49 MB, round 3).
// Swapped MFMA operands. N = output row stride.
// EPI: 0 = bias->f16 ; 2 = bias+gelu->f16.
// =====================================================================
template<int EPI>
__global__ __launch_bounds__(512, 2)
void gemm256(const f16* __restrict__ Ag, const f16* __restrict__ BTg,
             const float* __restrict__ biasg, void* __restrict__ outg,
             int NZ, int gridN, int N, int K, int lda,
             long zsB, long zsBias, long zsC)
{
    const int tid = threadIdx.x;
    const int w = tid >> 6, lane = tid & 63;
    const int wm = w >> 2, wn = w & 3;
    const int r16 = lane & 15, q4 = lane >> 4;

    const int cpx = gridDim.x >> 3;
    const int id  = (blockIdx.x & 7) * cpx + (blockIdx.x >> 3);

    const int nz   = id % NZ;
    const int mloc = id / NZ;
    const int z    = nz / gridN;
    const int nt   = nz - z * gridN;
    const int tm = mloc * 256, tn = nt * 256;

    const f16*   BT   = BTg + (size_t)z * zsB;
    const float* bias = biasg + (size_t)z * zsBias;
    const size_t zoffC = (size_t)z * zsC;

    __shared__ __align__(16) f16 smA[2][2][16][64][8];   // 64 KB
    __shared__ __align__(16) f16 smB[2][2][16][64][8];   // 64 KB

    const f16* gA[4]; const f16* gB[4];
#pragma unroll
    for (int t = 0; t < 4; ++t) {
        const int c = 4 * w + t, kk = c >> 4, rc = c & 15;
        gA[t] = Ag + (size_t)(tm + rc * 16 + r16) * lda + kk * 32 + q4 * 8;
        gB[t] = BT + (size_t)(tn + rc * 16 + r16) * K  + kk * 32 + q4 * 8;
    }
    f16* const smAbase = &smA[0][0][0][0][0];
    f16* const smBbase = &smB[0][0][0][0][0];
    const int coff = (4 * w) * 512;

    auto issue = [&](int kt, int buf) {
        const size_t o = (size_t)kt * 64;
        const int bo = buf * 16384 + coff;
#pragma unroll
        for (int t = 0; t < 4; ++t) {
            gld_lds16(gA[t] + o, smAbase + bo + t * 512);
            gld_lds16(gB[t] + o, smBbase + bo + t * 512);
        }
    };

    f32x4 acc[8][4];
#pragma unroll
    for (int i = 0; i < 8; ++i)
#pragma unroll
        for (int j = 0; j < 4; ++j) acc[i][j] = (f32x4)0.0f;

    const int iters = K >> 6;                   // BK = 64
    issue(0, 0);
    __builtin_amdgcn_s_waitcnt(0x0F70);         // vmcnt(0)
    __builtin_amdgcn_s_barrier();
    __asm__ __volatile__("" ::: "memory");

    for (int kt = 0; kt < iters; ++kt) {
        const int cur = kt & 1;
        const bool more = (kt + 1 < iters);
        if (more) issue(kt + 1, cur ^ 1);
#pragma unroll
        for (int kk = 0; kk < 2; ++kk) {
            f16x8 af[8], bf[4];
#pragma unroll
            for (int i = 0; i < 8; ++i)
                af[i] = *(const f16x8*)&smA[cur][kk][wm * 8 + i][lane][0];
#pragma unroll
            for (int j = 0; j < 4; ++j)
                bf[j] = *(const f16x8*)&smB[cur][kk][wn * 4 + j][lane][0];
            // swapped operands: acc[i][j] = C[m = i*16 + r16]
            //                                [n = j*16 + q4*4 + r]
#pragma unroll
            for (int i = 0; i < 8; ++i)
#pragma unroll
                for (int j = 0; j < 4; ++j)
                    acc[i][j] = __builtin_amdgcn_mfma_f32_16x16x32_f16(
                        bf[j], af[i], acc[i][j], 0, 0, 0);
        }
        if (more) {
            __builtin_amdgcn_s_waitcnt(0x0F70);
            __builtin_amdgcn_s_barrier();
            __asm__ __volatile__("" ::: "memory");
        }
    }

    const int rowBase = tm + wm * 128;
    const int colBase = tn + wn * 64;
#pragma unroll
    for (int i = 0; i < 8; ++i) {
        const int row = rowBase + i * 16 + r16;
        const size_t rowoff = (size_t)row * N;
#pragma unroll
        for (int j = 0; j < 4; ++j) {
            const int n0 = colBase + j * 16 + q4 * 4;
            const f32x4 bv4 = *(const f32x4*)&bias[n0];
            f16x4 o;
#pragma unroll
            for (int r = 0; r < 4; ++r) {
                float v = acc[i][j][r] + bv4[r];
                if constexpr (EPI == 2) {
                    // gelu_tanh(v) = v - v * rcp(exp(K*t)+1)
                    float v2 = v * v;
                    float t  = v * (1.0f + 0.044715f * v2);
                    float e  = __expf(1.5957691216057308f * t);
                    float rc = __builtin_amdgcn_rcpf(e + 1.0f);
                    v = v - v * rc;
                }
                o[r] = (f16)v;
            }
            *(f16x4*)((f16*)outg + zoffC + rowoff + n0) = o;
        }
    }
}

// =====================================================================
// gemm_bt2: 4-wave 128x128 kernel (compress GEMM only, EPI=3 -> f32)
// =====================================================================
template<int EPI>
__global__ __launch_bounds__(256, 4)
void gemm_bt2(const f16* __restrict__ Ag, const f16* __restrict__ BTg,
              const float* __restrict__ biasg, void* __restrict__ outg,
              int NZ, int gridN, int N, int K, int lda,
              long zsB, long zsBias, long zsC)
{
    const int tid  = threadIdx.x;
    const int w    = tid >> 6, lane = tid & 63;
    const int wm   = w >> 1,   wn   = w & 1;
    const int r16  = lane & 15, q4 = lane >> 4;

    const int cpx = gridDim.x >> 3;
    const int id  = (gridDim.x >= 8) ? ((blockIdx.x & 7) * cpx + (blockIdx.x >> 3))
                                     : blockIdx.x;

    const int nz   = id % NZ;
    const int mloc = id / NZ;
    const int z    = nz / gridN;
    const int nt   = nz - z * gridN;
    const int tm   = mloc * 128, tn = nt * 128;

    const f16*   BT   = BTg + (size_t)z * zsB;
    const float* bias = biasg + (size_t)z * zsBias;
    const size_t zoffC = (size_t)z * zsC;

    __shared__ __align__(16) f16 smA[2][8][64][8];
    __shared__ __align__(16) f16 smB[2][8][64][8];

    const int iters = K >> 5;

    const f16* gA0 = Ag + (size_t)(tm + (2 * w) * 16 + r16) * lda + q4 * 8;
    const f16* gA1 = gA0 + (size_t)16 * lda;
    const f16* gB0 = BT + (size_t)(tn + (2 * w) * 16 + r16) * K + q4 * 8;
    const f16* gB1 = gB0 + (size_t)16 * K;

    auto issue = [&](int kt, int buf) {
        const size_t o = (size_t)kt * 32;
        gld_lds16(gA0 + o, &smA[buf][2 * w][0][0]);
        gld_lds16(gA1 + o, &smA[buf][2 * w + 1][0][0]);
        gld_lds16(gB0 + o, &smB[buf][2 * w][0][0]);
        gld_lds16(gB1 + o, &smB[buf][2 * w + 1][0][0]);
    };

    f32x4 acc[4][4];
#pragma unroll
    for (int i = 0; i < 4; ++i)
#pragma unroll
        for (int j = 0; j < 4; ++j) acc[i][j] = (f32x4)0.0f;

    issue(0, 0);
    for (int kt = 0; kt < iters; ++kt) {
        const int cur = kt & 1;
        __builtin_amdgcn_s_barrier();
        if (kt + 1 < iters) {
            issue(kt + 1, cur ^ 1);
            __builtin_amdgcn_s_waitcnt(0x0F74);  // vmcnt(4)
        } else {
            __builtin_amdgcn_s_waitcnt(0x0F70);  // vmcnt(0)
        }
        __builtin_amdgcn_s_barrier();
        __asm__ __volatile__("" ::: "memory");

        f16x8 af[4], bf[4];
#pragma unroll
        for (int i = 0; i < 4; ++i) {
            af[i] = *(const f16x8*)&smA[cur][wm * 4 + i][lane][0];
            bf[i] = *(const f16x8*)&smB[cur][wn * 4 + i][lane][0];
        }
#pragma unroll
        for (int i = 0; i < 4; ++i)
#pragma unroll
            for (int j = 0; j < 4; ++j)
                acc[i][j] = __builtin_amdgcn_mfma_f32_16x16x32_f16(
                    bf[j], af[i], acc[i][j], 0, 0, 0);
    }

    const int rowBase = tm + wm * 64;
    const int colBase = tn + wn * 64;
#pragma unroll
    for (int i = 0; i < 4; ++i) {
        const int row = rowBase + i * 16 + r16;
        const size_t rowoff = (size_t)row * N;
#pragma unroll
        for (int j = 0; j < 4; ++j) {
            const int n0 = colBase + j * 16 + q4 * 4;
            const f32x4 bv4 = *(const f32x4*)&bias[n0];
            if constexpr (EPI == 3) {
                f32x4 o;
#pragma unroll
                for (int r = 0; r < 4; ++r) o[r] = acc[i][j][r] + bv4[r];
                *(f32x4*)((float*)outg + rowoff + n0) = o;
            } else {
                f16x4 o;
#pragma unroll
                for (int r = 0; r < 4; ++r) o[r] = (f16)(acc[i][j][r] + bv4[r]);
                *(f16x4*)((f16*)outg + zoffC + rowoff + n0) = o;
            }
        }
    }
}

// =====================================================================
// gemm_ln: 8-wave 128x512 fused GEMM + bias + residual + LayerNorm.
// lda: A row stride; rstride: residual row stride; output compact 512.
// =====================================================================
__global__ __launch_bounds__(512, 2)
void gemm_ln(const f16* __restrict__ Ag, const f16* __restrict__ BTg,
             const float* __restrict__ bias, const f16* __restrict__ resg,
             const float* __restrict__ lng, const float* __restrict__ lnb,
             f16* __restrict__ Yg, int K, int lda, int rstride)
{
    const int tid = threadIdx.x;
    const int w = tid >> 6, lane = tid & 63;
    const int wm = w >> 2, wn = w & 3;
    const int r16 = lane & 15, q4 = lane >> 4;
    const int tm = blockIdx.x * 128;

    __shared__ __align__(16) f16 smA[2][8][64][8];    // 16 KB
    __shared__ __align__(16) f16 smB[2][32][64][8];   // 64 KB
    __shared__ __align__(16) float lnS[128][4];
    __shared__ __align__(16) float lnQ[128][4];

    f32x4 acc[4][8];
#pragma unroll
    for (int i = 0; i < 4; ++i)
#pragma unroll
        for (int j = 0; j < 8; ++j) acc[i][j] = (f32x4)0.0f;

    const f16* gA  = Ag  + (size_t)(tm + w * 16 + r16) * lda + q4 * 8;
    const f16* gB  = BTg + (size_t)(w * 64 + r16) * K + q4 * 8;
    const int iters = K >> 5;

    auto issue = [&](int kt, int buf) {
        const size_t o = (size_t)kt * 32;
        gld_lds16(gA + o, &smA[buf][w][0][0]);
#pragma unroll
        for (int t = 0; t < 4; ++t)
            gld_lds16(gB + (size_t)(t * 16) * K + o, &smB[buf][w * 4 + t][0][0]);
    };

    issue(0, 0);
    for (int kt = 0; kt < iters; ++kt) {
        const int cur = kt & 1;
        __builtin_amdgcn_s_barrier();
        if (kt + 1 < iters) {
            issue(kt + 1, cur ^ 1);
            __builtin_amdgcn_s_waitcnt(0x0F75);  // vmcnt(5)
        } else {
            __builtin_amdgcn_s_waitcnt(0x0F70);  // vmcnt(0)
        }
        __builtin_amdgcn_s_barrier();
        __asm__ __volatile__("" ::: "memory");

        f16x8 af[4], bf[8];
#pragma unroll
        for (int i = 0; i < 4; ++i)
            af[i] = *(const f16x8*)&smA[cur][wm * 4 + i][lane][0];
#pragma unroll
        for (int j = 0; j < 8; ++j)
            bf[j] = *(const f16x8*)&smB[cur][wn * 8 + j][lane][0];
#pragma unroll
        for (int i = 0; i < 4; ++i)
#pragma unroll
            for (int j = 0; j < 8; ++j)
                acc[i][j] = __builtin_amdgcn_mfma_f32_16x16x32_f16(
                    bf[j], af[i], acc[i][j], 0, 0, 0);
    }

    const int rowB = wm * 64;
    const int colB = wn * 128;

    float ps[4], pq[4];
#pragma unroll
    for (int i = 0; i < 4; ++i) {
        const int grow = tm + rowB + i * 16 + r16;
        const size_t roff = (size_t)grow * rstride;
        float s = 0.f, sq = 0.f;
#pragma unroll
        for (int j = 0; j < 8; ++j) {
            const int n0 = colB + j * 16 + q4 * 4;
            const f32x4 biv = *(const f32x4*)&bias[n0];
            const f16x4 rv  = *(const f16x4*)&resg[roff + n0];
#pragma unroll
            for (int r = 0; r < 4; ++r) {
                float v = acc[i][j][r] + biv[r] + (float)rv[r];
                acc[i][j][r] = v;
                s += v; sq += v * v;
            }
        }
        s  += __shfl_xor(s, 16, 64);  s  += __shfl_xor(s, 32, 64);
        sq += __shfl_xor(sq, 16, 64); sq += __shfl_xor(sq, 32, 64);
        ps[i] = s; pq[i] = sq;
    }
    if (q4 == 0) {
#pragma unroll
        for (int i = 0; i < 4; ++i) {
            const int lr = rowB + i * 16 + r16;
            lnS[lr][wn] = ps[i];
            lnQ[lr][wn] = pq[i];
        }
    }
    __syncthreads();

#pragma unroll
    for (int i = 0; i < 4; ++i) {
        const int lr = rowB + i * 16 + r16;
        const f32x4 s4 = *(const f32x4*)&lnS[lr][0];
        const f32x4 q4v = *(const f32x4*)&lnQ[lr][0];
        const float s  = s4[0] + s4[1] + s4[2] + s4[3];
        const float sq = q4v[0] + q4v[1] + q4v[2] + q4v[3];
        const float mu = s * (1.0f / 512.0f);
        const float var = sq * (1.0f / 512.0f) - mu * mu;
        const float rs = rsqrtf(var + 1e-5f);
        const size_t rowoff = (size_t)(tm + lr) * 512;
#pragma unroll
        for (int j = 0; j < 8; ++j) {
            const int n0 = colB + j * 16 + q4 * 4;
            const f32x4 g4 = *(const f32x4*)&lng[n0];
            const f32x4 b4 = *(const f32x4*)&lnb[n0];
            f16x4 o;
#pragma unroll
            for (int r = 0; r < 4; ++r)
                o[r] = (f16)(g4[r] * (acc[i][j][r] - mu) * rs + b4[r]);
            *(f16x4*)&Yg[rowoff + n0] = o;
        }
    }
}

// =====================================================================
// Attention: mode 0 = full (16384 slabs); mode 1 = layer-0 dedup input.
// =====================================================================
__global__ __launch_bounds__(256)
void attn_kernel(const f16* __restrict__ qg, const f16* __restrict__ kg,
                 const f16* __restrict__ vg, const float* __restrict__ biasL,
                 f16* __restrict__ cg, int mode)
{
    const int w = threadIdx.x >> 6, lane = threadIdx.x & 63;
    const int j = blockIdx.x * 4 + w;
    __shared__ __align__(16) f16 sQ[4][8][136];
    __shared__ __align__(16) f16 sK[4][8][136];
    __shared__ __align__(16) f16 sV[4][8][136];
    __shared__ float sP[4][8][8];

    const size_t base  = (size_t)j * 1024;
    const size_t ibase = (mode == 1)
        ? ((size_t)(j >> 7) * 4096 + (size_t)(j & 3) * 1024) : base;
#pragma unroll
    for (int t = 0; t < 2; ++t) {
        int flat = (t * 64 + lane) * 8;
        int r = flat >> 7, c = flat & 127;
        *(f16x8*)&sQ[w][r][c] = *(const f16x8*)(qg + ibase + flat);
        *(f16x8*)&sK[w][r][c] = *(const f16x8*)(kg + ibase + flat);
        *(f16x8*)&sV[w][r][c] = *(const f16x8*)(vg + ibase + flat);
    }
    __syncthreads();

    const int i = lane >> 3, jj = lane & 7;
    float d = 0.f;
#pragma unroll
    for (int c = 0; c < 16; ++c) {
        f16x8 qv = *(const f16x8*)&sQ[w][i][c * 8];
        f16x8 kv = *(const f16x8*)&sK[w][jj][c * 8];
#pragma unroll
        for (int e = 0; e < 8; ++e) d += (float)qv[e] * (float)kv[e];
    }
    float s = d * 0.17677669529663687f + biasL[(size_t)(j & 4095) * 64 + lane];
    float mx = s;
    mx = fmaxf(mx, __shfl_xor(mx, 1, 64));
    mx = fmaxf(mx, __shfl_xor(mx, 2, 64));
    mx = fmaxf(mx, __shfl_xor(mx, 4, 64));
    float p = __expf(s - mx);
    float sum = p;
    sum += __shfl_xor(sum, 1, 64);
    sum += __shfl_xor(sum, 2, 64);
    sum += __shfl_xor(sum, 4, 64);
    sP[w][i][jj] = p / sum;
    __syncthreads();

#pragma unroll
    for (int t2 = 0; t2 < 8; ++t2) {
        float ap[8];
#pragma unroll
        for (int e = 0; e < 8; ++e) ap[e] = sP[w][t2][e];
#pragma unroll
        for (int h = 0; h < 2; ++h) {
            int flat = (t2 * 2 + h) * 64 + lane;
            int dd = flat & 127;
            float o = 0.f;
#pragma unroll
            for (int e = 0; e < 8; ++e) o += ap[e] * (float)sV[w][e][dd];
            cg[base + flat] = (f16)o;
        }
    }
}

// =====================================================================
// x0 builders / preamble kernels
// =====================================================================
__global__ __launch_bounds__(256)
void build_x0(const void* __restrict__ sup, const void* __restrict__ cls,
              f16* __restrict__ xb, const int* __restrict__ flag)
{
    const int f32 = *flag;
    const size_t idx = ((size_t)blockIdx.x * 256 + threadIdx.x) * 4;
    const int row = (int)(idx >> 9), col0 = (int)(idx & 511);
    const int s = row & 7, b = row >> 8;
    f16x4 o;
#pragma unroll
    for (int e = 0; e < 4; ++e) {
        const int md = (col0 + e) & 127;
        float v = (s == 0) ? ldf(cls, md, f32)
                           : ldf(sup, ((size_t)b * 7 + (s - 1)) * 128 + md, f32);
        o[e] = (f16)v;
    }
    *(f16x4*)(xb + idx) = o;
}

__global__ __launch_bounds__(256)
void build_x0s(const void* __restrict__ sup, const void* __restrict__ cls,
               f16* __restrict__ xs, const int* __restrict__ flag)
{
    const int f32 = *flag;
    const size_t idx = ((size_t)blockIdx.x * 256 + threadIdx.x) * 4;
    const int row = (int)(idx >> 9), col0 = (int)(idx & 511);
    const int s = row & 7, b = row >> 3;
    f16x4 o;
#pragma unroll
    for (int e = 0; e < 4; ++e) {
        const int md = (col0 + e) & 127;
        float v = (s == 0) ? ldf(cls, md, f32)
                           : ldf(sup, ((size_t)b * 7 + (s - 1)) * 128 + md, f32);
        o[e] = (f16)v;
    }
    *(f16x4*)(xs + idx) = o;
}

__global__ __launch_bounds__(256)
void bias_kernel(const void* __restrict__ qt, const void* __restrict__ st,
                 const void* __restrict__ freq, const void* __restrict__ phase,
                 const void* __restrict__ tw, float* __restrict__ biasAll,
                 const int* __restrict__ flag)
{
    const int f32 = *flag;
    const int lane = threadIdx.x & 63;
    const int bq = blockIdx.x * 4 + (threadIdx.x >> 6);
    const int b = bq >> 5, qq = bq & 31;
    const int i = lane >> 3, jj = lane & 7;
    const float ti = (i  == 0) ? ldf(qt, b * 32 + qq, f32) : ldf(st, b * 7 + i  - 1, f32);
    const float tj = (jj == 0) ? ldf(qt, b * 32 + qq, f32) : ldf(st, b * 7 + jj - 1, f32);
    const float td = ti - tj;
    float a[6] = {0.f, 0.f, 0.f, 0.f, 0.f, 0.f};
    for (int t = 0; t < 32; ++t) {
        float c = __cosf(td * ldf(freq, t, f32) + ldf(phase, t, f32));
#pragma unroll
        for (int l = 0; l < 6; ++l) a[l] += c * ldf(tw, l * 32 + t, f32);
    }
#pragma unroll
    for (int l = 0; l < 6; ++l)
        biasAll[(size_t)l * (4096 * 64) + (size_t)bq * 64 + lane] = a[l];
}

__global__ __launch_bounds__(256)
void transpose_cvt(const void* __restrict__ W, f16* __restrict__ WT,
                   int K, int N, long zsW, long zsWT, const int* __restrict__ flag)
{
    const int f32 = *flag;
    const size_t zoff = (size_t)blockIdx.z * zsW;
    f16* WTz = WT + (size_t)blockIdx.z * zsWT;
    __shared__ float tile[64][65];
    const int tn = blockIdx.x * 64, tk = blockIdx.y * 64;
#pragma unroll
    for (int t = 0; t < 16; ++t) {
        int idx = t * 256 + threadIdx.x;
        int r = idx >> 6, c = idx & 63;
        tile[r][c] = ldf(W, zoff + (size_t)(tk + r) * N + tn + c, f32);
    }
    __syncthreads();
#pragma unroll
    for (int t = 0; t < 16; ++t) {
        int idx = t * 256 + threadIdx.x;
        int r = idx >> 6, c = idx & 63;
        WTz[(size_t)(tn + r) * K + tk + c] = (f16)tile[c][r];
    }
}

__global__ __launch_bounds__(256)
void gather_qkvb(const void* __restrict__ bq, const void* __restrict__ bk,
                 const void* __restrict__ bv, float* __restrict__ dst,
                 const int* __restrict__ flag)
{
    const int f32 = *flag;
    int i = blockIdx.x * 256 + threadIdx.x;
    if (i < 9216) {
        int z = i / 3072, rem = i % 3072;
        const void* src = (z == 0) ? bq : ((z == 1) ? bk : bv);
        dst[i] = ldf(src, rem, f32);
    }
}

__global__ __launch_bounds__(256)
void bn_reduce(const float* __restrict__ h0, float* __restrict__ stats)
{
    const int t = blockIdx.x * 256 + threadIdx.x;
    float s = 0.f, ss = 0.f;
#pragma unroll
    for (int k = 0; k < 8; ++k) {
        float v = h0[t + k * 65536];
        s += v; ss += v * v;
    }
#pragma unroll
    for (int m = 1; m <= 32; m <<= 1) {
        s  += __shfl_xor(s, m, 64);
        ss += __shfl_xor(ss, m, 64);
    }
    __shared__ float ls[8];
    const int w = threadIdx.x >> 6, lane = threadIdx.x & 63;
    if (lane == 0) { ls[w] = s; ls[4 + w] = ss; }
    __syncthreads();
    if (threadIdx.x == 0) {
        atomicAdd(&stats[0], ls[0] + ls[1] + ls[2] + ls[3]);
        atomicAdd(&stats[1], ls[4] + ls[5] + ls[6] + ls[7]);
    }
}

__global__ __launch_bounds__(256)
void bn_apply(const float* __restrict__ h0, const float* __restrict__ stats,
              const float* __restrict__ bnp, float* __restrict__ out)
{
    const int t = blockIdx.x * 256 + threadIdx.x;
    const float mu  = stats[0] * (1.0f / 524288.0f);
    const float var = stats[1] * (1.0f / 524288.0f) - mu * mu;
    const float rs  = rsqrtf(var + 1e-5f);
    float v = bnp[0] * (h0[t] - mu) * rs + bnp[8];
    v = (v >= 0.f) ? v : 0.01f * v;
    out[t] = v;
}

// =====================================================================
extern "C" void kernel_launch(void* const* d_in, const int* in_sizes, int n_in,
                              void* d_out, int out_size, void* d_ws, size_t ws_size,
                              hipStream_t stream)
{
    (void)in_sizes; (void)n_in; (void)out_size;
    const void* sup   = d_in[0];
    const void* qt    = d_in[1];
    const void* st    = d_in[2];
    const void* cls   = d_in[3];
    const void* freq  = d_in[4];
    const void* phase = d_in[5];
    const void* Wq = d_in[6];  const void* bqv = d_in[7];
    const void* Wk = d_in[8];  const void* bkv = d_in[9];
    const void* Wv = d_in[10]; const void* bvv = d_in[11];
    const void* Wo = d_in[12]; const void* bo  = d_in[13];
    const void* ln1g = d_in[14]; const void* ln1b = d_in[15];
    const void* tw = d_in[16];
    const void* W1 = d_in[17]; const void* b1 = d_in[18];
    const void* W2 = d_in[19]; const void* b2 = d_in[20];
    const void* ln2g = d_in[21]; const void* ln2b = d_in[22];
    const void* Wc = d_in[23]; const void* bc = d_in[24];
    const void* bng = d_in[25]; const void* bnb = d_in[26];

    const size_t NEEDED = 245658240;
    if (ws_size < NEEDED) {
        fill_out<<<2048, 256, 0, stream>>>((float*)d_out, 999.0f);
        return;
    }

    char* ws = (char*)d_ws;
    f16*   wt      = (f16*)(ws + 0);
    float* biasAll = (float*)(ws + 37879808);
    float* qkvb    = (float*)(ws + 44171264);
    float* prm     = (float*)(ws + 44208128);
    float* stats   = (float*)(ws + 44331584);
    int*   flag    = (int*)  (ws + 44331592);
    f16*   xb      = (f16*)(ws + 44331648);
    f16*   ob      = (f16*)(ws + 77886080);
    char*  region  = ws + 111440512;
    f16*   qb      = (f16*)(region);
    f16*   kb      = (f16*)(region + 33554432);
    f16*   vb      = (f16*)(region + 67108864);
    f16*   cb      = (f16*)(region + 100663296);
    f16*   qs      = (f16*)(region);
    f16*   xs      = (f16*)(region + 100663296);
    f16*   fbuf    = (f16*)(region);
    float* h0      = (float*)(region);

    detect_dtype<<<1, 64, 0, stream>>>(qt, flag);

    cvt_in<<<12, 256, 0, stream>>>(bo,   prm + 0,     3072,  flag);
    cvt_in<<<48, 256, 0, stream>>>(b1,   prm + 3072,  12288, flag);
    cvt_in<<<12, 256, 0, stream>>>(b2,   prm + 15360, 3072,  flag);
    cvt_in<<<1,  256, 0, stream>>>(bc,   prm + 18432, 128,   flag);
    cvt_in<<<12, 256, 0, stream>>>(ln1g, prm + 18560, 3072,  flag);
    cvt_in<<<12, 256, 0, stream>>>(ln1b, prm + 21632, 3072,  flag);
    cvt_in<<<12, 256, 0, stream>>>(ln2g, prm + 24704, 3072,  flag);
    cvt_in<<<12, 256, 0, stream>>>(ln2b, prm + 27776, 3072,  flag);
    cvt_in<<<1,  256, 0, stream>>>(bng,  prm + 30848, 8,     flag);
    cvt_in<<<1,  256, 0, stream>>>(bnb,  prm + 30856, 8,     flag);

    transpose_cvt<<<dim3(8, 8, 6),  256, 0, stream>>>(Wq, wt + 0,        512, 512,  262144, 262144, flag);
    transpose_cvt<<<dim3(8, 8, 6),  256, 0, stream>>>(Wk, wt + 1572864,  512, 512,  262144, 262144, flag);
    transpose_cvt<<<dim3(8, 8, 6),  256, 0, stream>>>(Wv, wt + 3145728,  512, 512,  262144, 262144, flag);
    transpose_cvt<<<dim3(8, 8, 6),  256, 0, stream>>>(Wo, wt + 4718592,  512, 512,  262144, 262144, flag);
    transpose_cvt<<<dim3(32, 8, 6), 256, 0, stream>>>(W1, wt + 6291456,  512, 2048, 1048576, 1048576, flag);
    transpose_cvt<<<dim3(8, 32, 6), 256, 0, stream>>>(W2, wt + 12582912, 2048, 512, 1048576, 1048576, flag);
    transpose_cvt<<<dim3(2, 8, 1),  256, 0, stream>>>(Wc, wt + 18874368, 512, 128,  0, 0, flag);
    gather_qkvb<<<36, 256, 0, stream>>>(bqv, bkv, bvv, qkvb, flag);
    build_x0<<<16384, 256, 0, stream>>>(sup, cls, xb, flag);
    build_x0s<<<512, 256, 0, stream>>>(sup, cls, xs, flag);
    bias_kernel<<<1024, 256, 0, stream>>>(qt, st, freq, phase, tw, biasAll, flag);
    hipMemsetAsync(stats, 0, 8, stream);

    for (int l = 0; l < 6; ++l) {
        if (l == 0) {
            // QKV on deduped x0: M=1024 (4 m-tiles), NZ = 2 nt * 3 z = 6
            gemm256<0><<<24, 512, 0, stream>>>(
                xs, wt, qkvb, qs,
                6, 2, 512, 512, 512, 1572864, 3072, 524288);
            attn_kernel<<<4096, 256, 0, stream>>>(
                qs, qs + 524288, qs + 1048576, biasAll, cb, 1);
        } else {
            // QKV: M=32768 (128 m-tiles), NZ = 2 nt * 3 z = 6
            gemm256<0><<<768, 512, 0, stream>>>(
                xb, wt + l * 262144, qkvb + l * 512, qb,
                6, 2, 512, 512, 512, 1572864, 3072, 16777216);
            attn_kernel<<<4096, 256, 0, stream>>>(
                qb, kb, vb, biasAll + (size_t)l * 262144, cb, 0);
        }
        // O-proj + bias + residual(xb) + LN1 -> ob  (fused)
        gemm_ln<<<256, 512, 0, stream>>>(
            cb, wt + 4718592 + l * 262144, prm + 0 + l * 512, xb,
            prm + 18560 + l * 512, prm + 21632 + l * 512, ob, 512, 512, 512);
        if (l < 5) {
            // FFN1 + gelu -> fbuf : 128 m x 8 n = 1024 blocks
            gemm256<2><<<1024, 512, 0, stream>>>(
                ob, wt + 6291456 + l * 1048576, prm + 3072 + l * 2048, fbuf,
                8, 8, 2048, 512, 512, 0, 0, 0);
            // FFN2 + bias + residual(ob) + LN2 -> xb
            gemm_ln<<<256, 512, 0, stream>>>(
                fbuf, wt + 12582912 + l * 1048576, prm + 15360 + l * 512, ob,
                prm + 24704 + l * 512, prm + 27776 + l * 512, xb, 2048, 2048, 512);
        } else {
            // Last layer: only s==0 rows feed compress. M = 4096.
            // FFN1 on strided rows of ob (row r -> ob row 8r, lda=4096)
            gemm256<2><<<128, 512, 0, stream>>>(
                ob, wt + 6291456 + l * 1048576, prm + 3072 + l * 2048, fbuf,
                8, 8, 2048, 512, 4096, 0, 0, 0);
            // FFN2 + residual(ob strided) + LN2 -> cb compact [4096,512]
            gemm_ln<<<32, 512, 0, stream>>>(
                fbuf, wt + 12582912 + l * 1048576, prm + 15360 + l * 512, ob,
                prm + 24704 + l * 512, prm + 27776 + l * 512, cb, 2048, 2048, 4096);
        }
    }

    // compress on compact [4096,512] CLS rows
    gemm_bt2<3><<<32, 256, 0, stream>>>(
        cb, wt + 18874368, prm + 18432, h0,
        1, 1, 128, 512, 512, 0, 0, 0);
    bn_reduce<<<256, 256, 0, stream>>>(h0, stats);
    bn_apply<<<2048, 256, 0, stream>>>(h0, stats, prm + 30848, (float*)d_out);
}

// Round 13
// 2574.055 us; speedup vs baseline: 1.0841x; 1.0571x over previous
//
#include <hip/hip_runtime.h>
#include <hip/hip_bf16.h>

typedef _Float16 f16;
typedef __attribute__((ext_vector_type(8))) _Float16 f16x8;
typedef __attribute__((ext_vector_type(4))) _Float16 f16x4;
typedef __attribute__((ext_vector_type(4))) float f32x4;

#define DEVI __device__ __forceinline__

DEVI float ldf(const void* p, size_t i, int isf32) {
    if (isf32) return ((const float*)p)[i];
    unsigned int u = ((const unsigned short*)p)[i];
    union { unsigned int b; float f; } c; c.b = u << 16;
    return c.f;
}

DEVI void gld_lds16(const f16* g, f16* l) {
    __builtin_amdgcn_global_load_lds(
        (__attribute__((address_space(1))) void*)(g),
        (__attribute__((address_space(3))) void*)(l), 16, 0, 0);
}

__global__ void detect_dtype(const void* qt, int* flag) {
    if (threadIdx.x == 0 && blockIdx.x == 0) {
        const unsigned int* w = (const unsigned int*)qt;
        int cnt = 0;
        for (int i = 0; i < 64; ++i) {
            unsigned int lo = w[i] & 0xFFFFu;
            union { unsigned int b; float f; } c; c.b = lo << 16;
            if (c.f >= 1e-4f && c.f <= 100.5f) ++cnt;
        }
        *flag = (cnt >= 32) ? 0 : 1;   // 0 = bf16, 1 = fp32
    }
}

__global__ __launch_bounds__(256)
void cvt_in(const void* __restrict__ src, float* __restrict__ dst, int n,
            const int* __restrict__ flag) {
    const int f32 = *flag;
    int i = blockIdx.x * 256 + threadIdx.x;
    if (i < n) dst[i] = ldf(src, i, f32);
}

__global__ __launch_bounds__(256)
void fill_out(float* out, float v) {
    out[blockIdx.x * 256 + threadIdx.x] = v;
}

// =====================================================================
// gemm256: 8-wave 256x256 MFMA GEMM, m201-style phased schedule.
// Stage = BK=32 half-tile; 4-slot LDS ring (128 KB, 1 block/CU).
// Prefetch 3 stages ahead; stage-exit gate vmcnt(8)/(4)/(0) counted.
// Per stage 2 phases: {ds_read -> issue gloads -> barrier -> lgkmcnt(0)
// + sched_barrier -> setprio(1) -> 16 MFMA -> setprio(0) -> barrier}.
// nz-fastest mapping + bijective XCD swizzle.
// Swapped MFMA operands: lane holds 4 consecutive output cols.
// EPI: 0 = bias->f16 ; 2 = bias+gelu->f16.
// MEASURED round-6 bench (this exact source): FFN1 150.3 us, total 2578.
// =====================================================================
template<int EPI>
__global__ __launch_bounds__(512, 2)
void gemm256(const f16* __restrict__ Ag, const f16* __restrict__ BTg,
             const float* __restrict__ biasg, void* __restrict__ outg,
             int NZ, int gridN, int N, int K, int lda,
             long zsB, long zsBias, long zsC)
{
    const int tid = threadIdx.x;
    const int w = tid >> 6, lane = tid & 63;
    const int wm = w >> 2, wn = w & 3;          // 2 (M) x 4 (N) wave grid
    const int r16 = lane & 15, q4 = lane >> 4;

    // bijective XCD swizzle (requires gridDim.x % 8 == 0)
    const int cpx = gridDim.x >> 3;
    const int id  = (blockIdx.x & 7) * cpx + (blockIdx.x >> 3);

    const int nz   = id % NZ;
    const int mloc = id / NZ;
    const int z    = nz / gridN;
    const int nt   = nz - z * gridN;
    const int tm = mloc * 256, tn = nt * 256;

    const f16*   BT   = BTg + (size_t)z * zsB;
    const float* bias = biasg + (size_t)z * zsBias;
    const size_t zoffC = (size_t)z * zsC;

    // [tile&1][kk][chunk16][lane][8] ; chunk = 16 rows x 32 k = 1 KB
    __shared__ __align__(16) f16 smA[2][2][16][64][8];   // 64 KB
    __shared__ __align__(16) f16 smB[2][2][16][64][8];   // 64 KB

    // wave w stages A chunks 2w,2w+1 and B chunks 2w,2w+1 of EVERY stage
    const int c0 = 2 * w, c1 = 2 * w + 1;
    const f16* gA0 = Ag + (size_t)(tm + c0 * 16 + r16) * lda + q4 * 8;
    const f16* gA1 = Ag + (size_t)(tm + c1 * 16 + r16) * lda + q4 * 8;
    const f16* gB0 = BT + (size_t)(tn + c0 * 16 + r16) * K  + q4 * 8;
    const f16* gB1 = BT + (size_t)(tn + c1 * 16 + r16) * K  + q4 * 8;

    auto issueA = [&](int s) {
        const int tb = (s >> 1) & 1, kk = s & 1;
        const size_t o = (size_t)s * 32;
        gld_lds16(gA0 + o, &smA[tb][kk][c0][0][0]);
        gld_lds16(gA1 + o, &smA[tb][kk][c1][0][0]);
    };
    auto issueB = [&](int s) {
        const int tb = (s >> 1) & 1, kk = s & 1;
        const size_t o = (size_t)s * 32;
        gld_lds16(gB0 + o, &smB[tb][kk][c0][0][0]);
        gld_lds16(gB1 + o, &smB[tb][kk][c1][0][0]);
    };

    f32x4 acc[8][4];
#pragma unroll
    for (int i = 0; i < 8; ++i)
#pragma unroll
        for (int j = 0; j < 4; ++j) acc[i][j] = (f32x4)0.0f;

    const int NS = K >> 5;                      // stages (>= 3)
    issueA(0); issueB(0); issueA(1); issueB(1); issueA(2); issueB(2);
    __builtin_amdgcn_s_waitcnt(0x0F78);         // vmcnt(8): stage 0 landed
    __asm__ __volatile__("" ::: "memory");
    __builtin_amdgcn_s_barrier();
    __asm__ __volatile__("" ::: "memory");

    for (int s = 0; s < NS; ++s) {
        const int tb = (s >> 1) & 1, kk = s & 1;
        f16x8 af[4], bf[4], ag[4];

        // ---- phase A: rows 0-63 of wave tile ----
#pragma unroll
        for (int i = 0; i < 4; ++i)
            af[i] = *(const f16x8*)&smA[tb][kk][wm * 8 + i][lane][0];
#pragma unroll
        for (int j = 0; j < 4; ++j)
            bf[j] = *(const f16x8*)&smB[tb][kk][wn * 4 + j][lane][0];
        if (s + 3 < NS) issueA(s + 3);
        __asm__ __volatile__("" ::: "memory");
        __builtin_amdgcn_s_barrier();
        __builtin_amdgcn_s_waitcnt(0xC07F);     // lgkmcnt(0)
        __builtin_amdgcn_sched_barrier(0);
        __builtin_amdgcn_s_setprio(1);
#pragma unroll
        for (int i = 0; i < 4; ++i)
#pragma unroll
            for (int j = 0; j < 4; ++j)
                acc[i][j] = __builtin_amdgcn_mfma_f32_16x16x32_f16(
                    bf[j], af[i], acc[i][j], 0, 0, 0);
        __builtin_amdgcn_s_setprio(0);
        __asm__ __volatile__("" ::: "memory");
        __builtin_amdgcn_s_barrier();
        __asm__ __volatile__("" ::: "memory");

        // ---- phase B: rows 64-127 of wave tile ----
#pragma unroll
        for (int i = 0; i < 4; ++i)
            ag[i] = *(const f16x8*)&smA[tb][kk][wm * 8 + 4 + i][lane][0];
        if (s + 3 < NS) issueB(s + 3);
        __asm__ __volatile__("" ::: "memory");
        __builtin_amdgcn_s_barrier();
        __builtin_amdgcn_s_waitcnt(0xC07F);     // lgkmcnt(0)
        __builtin_amdgcn_sched_barrier(0);
        __builtin_amdgcn_s_setprio(1);
#pragma unroll
        for (int i = 0; i < 4; ++i)
#pragma unroll
            for (int j = 0; j < 4; ++j)
                acc[4 + i][j] = __builtin_amdgcn_mfma_f32_16x16x32_f16(
                    bf[j], ag[i], acc[4 + i][j], 0, 0, 0);
        __builtin_amdgcn_s_setprio(0);

        // ---- stage-exit gate: next stage's loads landed (counted) ----
        if (s + 1 < NS) {
            if (s + 3 < NS)      __builtin_amdgcn_s_waitcnt(0x0F78); // vmcnt(8)
            else if (s + 2 < NS) __builtin_amdgcn_s_waitcnt(0x0F74); // vmcnt(4)
            else                 __builtin_amdgcn_s_waitcnt(0x0F70); // vmcnt(0)
        }
        __asm__ __volatile__("" ::: "memory");
        __builtin_amdgcn_s_barrier();
        __asm__ __volatile__("" ::: "memory");
    }

    const int rowBase = tm + wm * 128;
    const int colBase = tn + wn * 64;
#pragma unroll
    for (int i = 0; i < 8; ++i) {
        const int row = rowBase + i * 16 + r16;
        const size_t rowoff = (size_t)row * N;
#pragma unroll
        for (int j = 0; j < 4; ++j) {
            const int n0 = colBase + j * 16 + q4 * 4;
            const f32x4 bv4 = *(const f32x4*)&bias[n0];
            f16x4 o;
#pragma unroll
            for (int r = 0; r < 4; ++r) {
                float v = acc[i][j][r] + bv4[r];
                if constexpr (EPI == 2) {
                    // gelu_tanh(v) = v - v * rcp(exp(K*t)+1)
                    float v2 = v * v;
                    float t  = v * (1.0f + 0.044715f * v2);
                    float e  = __expf(1.5957691216057308f * t);
                    float rc = __builtin_amdgcn_rcpf(e + 1.0f);
                    v = v - v * rc;
                }
                o[r] = (f16)v;
            }
            *(f16x4*)((f16*)outg + zoffC + rowoff + n0) = o;
        }
    }
}

// =====================================================================
// gemm_bt: legacy 4-wave 128x128 kernel (compress GEMM, EPI=3 -> f32)
// =====================================================================
template<int EPI>
__global__ __launch_bounds__(256, 4)
void gemm_bt(const f16* __restrict__ Ag, const f16* __restrict__ BTg,
             const float* __restrict__ biasg, const f16* __restrict__ resg,
             void* __restrict__ outg,
             int NT, int NTZ, int MCHUNK, int MT, int N, int K, int lda,
             long zsB, long zsBias, long zsC)
{
    const int tid  = threadIdx.x;
    const int w    = tid >> 6, lane = tid & 63;
    const int wm   = w >> 1,   wn   = w & 1;

    const int id    = blockIdx.x;
    const int pc    = MCHUNK * NTZ;
    const int chunk = id / pc;
    const int rem   = id - chunk * pc;
    const int mloc  = rem % MCHUNK;
    const int ynz   = rem / MCHUNK;
    const int z     = ynz / NT;
    const int tmB   = (chunk * MCHUNK + mloc) * (128 * MT);
    const int tn    = (ynz - z * NT) * 128;

    const f16*   BT   = BTg + (size_t)z * zsB;
    const float* bias = biasg + (size_t)z * zsBias;
    const size_t zoffC = (size_t)z * zsC;

    __shared__ __align__(16) f16 smA[2][8][64][8];
    __shared__ __align__(16) f16 smB[2][8][64][8];

    const int r16 = lane & 15, q4 = lane >> 4;
    const int iters = K >> 5;

    const f16* gA0 = Ag + (size_t)(tmB + (2 * w) * 16 + r16) * lda + q4 * 8;
    const f16* gA1 = gA0 + (size_t)16 * lda;
    const f16* gB0 = BT + (size_t)(tn + (2 * w) * 16 + r16) * K + q4 * 8;
    const f16* gB1 = gB0 + (size_t)16 * K;

    auto issue = [&](int msN, int ktN, int buf) {
        const size_t aoff = (size_t)msN * 128 * lda + (size_t)ktN * 32;
        const size_t boff = (size_t)ktN * 32;
        gld_lds16(gA0 + aoff, &smA[buf][2 * w][0][0]);
        gld_lds16(gA1 + aoff, &smA[buf][2 * w + 1][0][0]);
        gld_lds16(gB0 + boff, &smB[buf][2 * w][0][0]);
        gld_lds16(gB1 + boff, &smB[buf][2 * w + 1][0][0]);
    };

    issue(0, 0, 0);
    int stage = 0;

    for (int ms = 0; ms < MT; ++ms) {
        const int tm = tmB + ms * 128;

        f32x4 acc[4][4];
#pragma unroll
        for (int i = 0; i < 4; ++i)
#pragma unroll
            for (int j = 0; j < 4; ++j) acc[i][j] = (f32x4)0.0f;

        for (int kt = 0; kt < iters; ++kt, ++stage) {
            const int cur = stage & 1;
            __builtin_amdgcn_s_barrier();
            int ktN = kt + 1, msN = ms;
            if (ktN == iters) { ktN = 0; ++msN; }
            if (msN < MT) {
                issue(msN, ktN, cur ^ 1);
                __builtin_amdgcn_s_waitcnt(0x0F74);  // vmcnt(4)
            } else {
                __builtin_amdgcn_s_waitcnt(0x0F70);  // vmcnt(0)
            }
            __builtin_amdgcn_s_barrier();
            __asm__ __volatile__("" ::: "memory");

            f16x8 af[4], bf[4];
#pragma unroll
            for (int i = 0; i < 4; ++i) {
                af[i] = *(const f16x8*)&smA[cur][wm * 4 + i][lane][0];
                bf[i] = *(const f16x8*)&smB[cur][wn * 4 + i][lane][0];
            }
#pragma unroll
            for (int i = 0; i < 4; ++i)
#pragma unroll
                for (int j = 0; j < 4; ++j)
                    acc[i][j] = __builtin_amdgcn_mfma_f32_16x16x32_f16(
                        bf[j], af[i], acc[i][j], 0, 0, 0);
        }

        const int rowBase = tm + wm * 64;
        const int colBase = tn + wn * 64;
#pragma unroll
        for (int i = 0; i < 4; ++i) {
            const int row = rowBase + i * 16 + r16;
            const size_t rowoff = (size_t)row * N;
#pragma unroll
            for (int j = 0; j < 4; ++j) {
                const int n0 = colBase + j * 16 + q4 * 4;
                const f32x4 bv4 = *(const f32x4*)&bias[n0];
                if constexpr (EPI == 3) {
                    f32x4 o;
#pragma unroll
                    for (int r = 0; r < 4; ++r) o[r] = acc[i][j][r] + bv4[r];
                    *(f32x4*)((float*)outg + rowoff + n0) = o;
                } else {
                    f16x4 o;
#pragma unroll
                    for (int r = 0; r < 4; ++r) {
                        float v = acc[i][j][r] + bv4[r];
                        if constexpr (EPI == 2) {
                            float v2 = v * v;
                            float t  = v * (1.0f + 0.044715f * v2);
                            float e  = __expf(1.5957691216057308f * t);
                            float rc = __builtin_amdgcn_rcpf(e + 1.0f);
                            v = v - v * rc;
                        }
                        o[r] = (f16)v;
                    }
                    *(f16x4*)((f16*)outg + zoffC + rowoff + n0) = o;
                }
            }
        }
    }
}

// =====================================================================
// gemm_ln: 8-wave 128x512 fused GEMM + bias + residual + LayerNorm.
// rstride: element stride between consecutive logical rows of resg
// (512 normal; 4096 for the s==0-pruned last layer).
// =====================================================================
__global__ __launch_bounds__(512, 2)
void gemm_ln(const f16* __restrict__ Ag, const f16* __restrict__ BTg,
             const float* __restrict__ bias, const f16* __restrict__ resg,
             const float* __restrict__ lng, const float* __restrict__ lnb,
             f16* __restrict__ Yg, int K, int lda, int rstride)
{
    const int tid = threadIdx.x;
    const int w = tid >> 6, lane = tid & 63;
    const int wm = w >> 2, wn = w & 3;
    const int r16 = lane & 15, q4 = lane >> 4;
    const int tm = blockIdx.x * 128;

    __shared__ __align__(16) f16 smA[2][8][64][8];    // 16 KB
    __shared__ __align__(16) f16 smB[2][32][64][8];   // 64 KB
    __shared__ __align__(16) float lnS[128][4];
    __shared__ __align__(16) float lnQ[128][4];

    f32x4 acc[4][8];
#pragma unroll
    for (int i = 0; i < 4; ++i)
#pragma unroll
        for (int j = 0; j < 8; ++j) acc[i][j] = (f32x4)0.0f;

    const f16* gA  = Ag  + (size_t)(tm + w * 16 + r16) * lda + q4 * 8;
    const f16* gB  = BTg + (size_t)(w * 64 + r16) * K + q4 * 8;
    const int iters = K >> 5;

    auto issue = [&](int kt, int buf) {
        const size_t o = (size_t)kt * 32;
        gld_lds16(gA + o, &smA[buf][w][0][0]);
#pragma unroll
        for (int t = 0; t < 4; ++t)
            gld_lds16(gB + (size_t)(t * 16) * K + o, &smB[buf][w * 4 + t][0][0]);
    };

    issue(0, 0);
    for (int kt = 0; kt < iters; ++kt) {
        const int cur = kt & 1;
        __builtin_amdgcn_s_barrier();
        if (kt + 1 < iters) {
            issue(kt + 1, cur ^ 1);
            __builtin_amdgcn_s_waitcnt(0x0F75);  // vmcnt(5): current 5 done
        } else {
            __builtin_amdgcn_s_waitcnt(0x0F70);  // vmcnt(0)
        }
        __builtin_amdgcn_s_barrier();
        __asm__ __volatile__("" ::: "memory");

        f16x8 af[4], bf[8];
#pragma unroll
        for (int i = 0; i < 4; ++i)
            af[i] = *(const f16x8*)&smA[cur][wm * 4 + i][lane][0];
#pragma unroll
        for (int j = 0; j < 8; ++j)
            bf[j] = *(const f16x8*)&smB[cur][wn * 8 + j][lane][0];
#pragma unroll
        for (int i = 0; i < 4; ++i)
#pragma unroll
            for (int j = 0; j < 8; ++j)
                acc[i][j] = __builtin_amdgcn_mfma_f32_16x16x32_f16(
                    bf[j], af[i], acc[i][j], 0, 0, 0);
    }

    // ---- epilogue: bias + residual, row stats, LN, store ----
    const int rowB = wm * 64;
    const int colB = wn * 128;

    float ps[4], pq[4];
#pragma unroll
    for (int i = 0; i < 4; ++i) {
        const int grow = tm + rowB + i * 16 + r16;
        const size_t roff = (size_t)grow * rstride;
        float s = 0.f, sq = 0.f;
#pragma unroll
        for (int j = 0; j < 8; ++j) {
            const int n0 = colB + j * 16 + q4 * 4;
            const f32x4 biv = *(const f32x4*)&bias[n0];
            const f16x4 rv  = *(const f16x4*)&resg[roff + n0];
#pragma unroll
            for (int r = 0; r < 4; ++r) {
                float v = acc[i][j][r] + biv[r] + (float)rv[r];
                acc[i][j][r] = v;
                s += v; sq += v * v;
            }
        }
        s  += __shfl_xor(s, 16, 64);  s  += __shfl_xor(s, 32, 64);
        sq += __shfl_xor(sq, 16, 64); sq += __shfl_xor(sq, 32, 64);
        ps[i] = s; pq[i] = sq;
    }
    if (q4 == 0) {
#pragma unroll
        for (int i = 0; i < 4; ++i) {
            const int lr = rowB + i * 16 + r16;
            lnS[lr][wn] = ps[i];
            lnQ[lr][wn] = pq[i];
        }
    }
    __syncthreads();

#pragma unroll
    for (int i = 0; i < 4; ++i) {
        const int lr = rowB + i * 16 + r16;
        const f32x4 s4 = *(const f32x4*)&lnS[lr][0];
        const f32x4 q4v = *(const f32x4*)&lnQ[lr][0];
        const float s  = s4[0] + s4[1] + s4[2] + s4[3];
        const float sq = q4v[0] + q4v[1] + q4v[2] + q4v[3];
        const float mu = s * (1.0f / 512.0f);
        const float var = sq * (1.0f / 512.0f) - mu * mu;
        const float rs = rsqrtf(var + 1e-5f);
        const size_t rowoff = (size_t)(tm + lr) * 512;
#pragma unroll
        for (int j = 0; j < 8; ++j) {
            const int n0 = colB + j * 16 + q4 * 4;
            const f32x4 g4 = *(const f32x4*)&lng[n0];
            const f32x4 b4 = *(const f32x4*)&lnb[n0];
            f16x4 o;
#pragma unroll
            for (int r = 0; r < 4; ++r)
                o[r] = (f16)(g4[r] * (acc[i][j][r] - mu) * rs + b4[r]);
            *(f16x4*)&Yg[rowoff + n0] = o;
        }
    }
}

// =====================================================================
// Attention: 1 wave per batch j in [0,16384)
// =====================================================================
__global__ __launch_bounds__(256)
void attn_kernel(const f16* __restrict__ qg, const f16* __restrict__ kg,
                 const f16* __restrict__ vg, const float* __restrict__ biasL,
                 f16* __restrict__ cg, int small)
{
    const int w = threadIdx.x >> 6, lane = threadIdx.x & 63;
    const int j = blockIdx.x * 4 + w;
    __shared__ __align__(16) f16 sQ[4][8][136];
    __shared__ __align__(16) f16 sK[4][8][136];
    __shared__ __align__(16) f16 sV[4][8][136];
    __shared__ float sP[4][8][8];

    const size_t base  = (size_t)j * 1024;
    const size_t ibase = small ? ((size_t)(j >> 7) * 4096 + (size_t)(j & 3) * 1024)
                               : base;
#pragma unroll
    for (int t = 0; t < 2; ++t) {
        int flat = (t * 64 + lane) * 8;
        int r = flat >> 7, c = flat & 127;
        *(f16x8*)&sQ[w][r][c] = *(const f16x8*)(qg + ibase + flat);
        *(f16x8*)&sK[w][r][c] = *(const f16x8*)(kg + ibase + flat);
        *(f16x8*)&sV[w][r][c] = *(const f16x8*)(vg + ibase + flat);
    }
    __syncthreads();

    const int i = lane >> 3, jj = lane & 7;
    float d = 0.f;
#pragma unroll
    for (int c = 0; c < 16; ++c) {
        f16x8 qv = *(const f16x8*)&sQ[w][i][c * 8];
        f16x8 kv = *(const f16x8*)&sK[w][jj][c * 8];
#pragma unroll
        for (int e = 0; e < 8; ++e) d += (float)qv[e] * (float)kv[e];
    }
    float s = d * 0.17677669529663687f + biasL[(size_t)(j & 4095) * 64 + lane];
    float mx = s;
    mx = fmaxf(mx, __shfl_xor(mx, 1, 64));
    mx = fmaxf(mx, __shfl_xor(mx, 2, 64));
    mx = fmaxf(mx, __shfl_xor(mx, 4, 64));
    float p = __expf(s - mx);
    float sum = p;
    sum += __shfl_xor(sum, 1, 64);
    sum += __shfl_xor(sum, 2, 64);
    sum += __shfl_xor(sum, 4, 64);
    sP[w][i][jj] = p / sum;
    __syncthreads();

#pragma unroll
    for (int t2 = 0; t2 < 8; ++t2) {
        float ap[8];
#pragma unroll
        for (int e = 0; e < 8; ++e) ap[e] = sP[w][t2][e];
#pragma unroll
        for (int h = 0; h < 2; ++h) {
            int flat = (t2 * 2 + h) * 64 + lane;
            int dd = flat & 127;
            float o = 0.f;
#pragma unroll
            for (int e = 0; e < 8; ++e) o += ap[e] * (float)sV[w][e][dd];
            cg[base + flat] = (f16)o;
        }
    }
}

// =====================================================================
// x0 builders
// =====================================================================
__global__ __launch_bounds__(256)
void build_x0(const void* __restrict__ sup, const void* __restrict__ cls,
              f16* __restrict__ xb, const int* __restrict__ flag)
{
    const int f32 = *flag;
    const size_t idx = ((size_t)blockIdx.x * 256 + threadIdx.x) * 4;
    const int row = (int)(idx >> 9), col0 = (int)(idx & 511);
    const int s = row & 7, b = row >> 8;
    f16x4 o;
#pragma unroll
    for (int e = 0; e < 4; ++e) {
        const int md = (col0 + e) & 127;
        float v = (s == 0) ? ldf(cls, md, f32)
                           : ldf(sup, ((size_t)b * 7 + (s - 1)) * 128 + md, f32);
        o[e] = (f16)v;
    }
    *(f16x4*)(xb + idx) = o;
}

__global__ __launch_bounds__(256)
void build_x0s(const void* __restrict__ sup, const void* __restrict__ cls,
               f16* __restrict__ xs, const int* __restrict__ flag)
{
    const int f32 = *flag;
    const size_t idx = ((size_t)blockIdx.x * 256 + threadIdx.x) * 4;
    const int row = (int)(idx >> 9), col0 = (int)(idx & 511);
    const int s = row & 7, b = row >> 3;
    f16x4 o;
#pragma unroll
    for (int e = 0; e < 4; ++e) {
        const int md = (col0 + e) & 127;
        float v = (s == 0) ? ldf(cls, md, f32)
                           : ldf(sup, ((size_t)b * 7 + (s - 1)) * 128 + md, f32);
        o[e] = (f16)v;
    }
    *(f16x4*)(xs + idx) = o;
}

__global__ __launch_bounds__(256)
void bias_kernel(const void* __restrict__ qt, const void* __restrict__ st,
                 const void* __restrict__ freq, const void* __restrict__ phase,
                 const void* __restrict__ tw, float* __restrict__ biasAll,
                 const int* __restrict__ flag)
{
    const int f32 = *flag;
    const int lane = threadIdx.x & 63;
    const int bq = blockIdx.x * 4 + (threadIdx.x >> 6);
    const int b = bq >> 5, qq = bq & 31;
    const int i = lane >> 3, jj = lane & 7;
    const float ti = (i  == 0) ? ldf(qt, b * 32 + qq, f32) : ldf(st, b * 7 + i  - 1, f32);
    const float tj = (jj == 0) ? ldf(qt, b * 32 + qq, f32) : ldf(st, b * 7 + jj - 1, f32);
    const float td = ti - tj;
    float a[6] = {0.f, 0.f, 0.f, 0.f, 0.f, 0.f};
    for (int t = 0; t < 32; ++t) {
        float c = __cosf(td * ldf(freq, t, f32) + ldf(phase, t, f32));
#pragma unroll
        for (int l = 0; l < 6; ++l) a[l] += c * ldf(tw, l * 32 + t, f32);
    }
#pragma unroll
    for (int l = 0; l < 6; ++l)
        biasAll[(size_t)l * (4096 * 64) + (size_t)bq * 64 + lane] = a[l];
}

__global__ __launch_bounds__(256)
void transpose_cvt(const void* __restrict__ W, f16* __restrict__ WT,
                   int K, int N, long zsW, long zsWT, const int* __restrict__ flag)
{
    const int f32 = *flag;
    const size_t zoff = (size_t)blockIdx.z * zsW;
    f16* WTz = WT + (size_t)blockIdx.z * zsWT;
    __shared__ float tile[64][65];
    const int tn = blockIdx.x * 64, tk = blockIdx.y * 64;
#pragma unroll
    for (int t = 0; t < 16; ++t) {
        int idx = t * 256 + threadIdx.x;
        int r = idx >> 6, c = idx & 63;
        tile[r][c] = ldf(W, zoff + (size_t)(tk + r) * N + tn + c, f32);
    }
    __syncthreads();
#pragma unroll
    for (int t = 0; t < 16; ++t) {
        int idx = t * 256 + threadIdx.x;
        int r = idx >> 6, c = idx & 63;
        WTz[(size_t)(tn + r) * K + tk + c] = (f16)tile[c][r];
    }
}

__global__ __launch_bounds__(256)
void gather_qkvb(const void* __restrict__ bq, const void* __restrict__ bk,
                 const void* __restrict__ bv, float* __restrict__ dst,
                 const int* __restrict__ flag)
{
    const int f32 = *flag;
    int i = blockIdx.x * 256 + threadIdx.x;
    if (i < 9216) {
        int z = i / 3072, rem = i % 3072;
        const void* src = (z == 0) ? bq : ((z == 1) ? bk : bv);
        dst[i] = ldf(src, rem, f32);
    }
}

__global__ __launch_bounds__(256)
void bn_reduce(const float* __restrict__ h0, float* __restrict__ stats)
{
    const int t = blockIdx.x * 256 + threadIdx.x;
    float s = 0.f, ss = 0.f;
#pragma unroll
    for (int k = 0; k < 8; ++k) {
        float v = h0[t + k * 65536];
        s += v; ss += v * v;
    }
#pragma unroll
    for (int m = 1; m <= 32; m <<= 1) {
        s  += __shfl_xor(s, m, 64);
        ss += __shfl_xor(ss, m, 64);
    }
    __shared__ float ls[8];
    const int w = threadIdx.x >> 6, lane = threadIdx.x & 63;
    if (lane == 0) { ls[w] = s; ls[4 + w] = ss; }
    __syncthreads();
    if (threadIdx.x == 0) {
        atomicAdd(&stats[0], ls[0] + ls[1] + ls[2] + ls[3]);
        atomicAdd(&stats[1], ls[4] + ls[5] + ls[6] + ls[7]);
    }
}

__global__ __launch_bounds__(256)
void bn_apply(const float* __restrict__ h0, const float* __restrict__ stats,
              const float* __restrict__ bnp, float* __restrict__ out)
{
    const int t = blockIdx.x * 256 + threadIdx.x;
    const float mu  = stats[0] * (1.0f / 524288.0f);
    const float var = stats[1] * (1.0f / 524288.0f) - mu * mu;
    const float rs  = rsqrtf(var + 1e-5f);
    float v = bnp[0] * (h0[t] - mu) * rs + bnp[8];
    v = (v >= 0.f) ? v : 0.01f * v;
    out[t] = v;
}

// =====================================================================
extern "C" void kernel_launch(void* const* d_in, const int* in_sizes, int n_in,
                              void* d_out, int out_size, void* d_ws, size_t ws_size,
                              hipStream_t stream)
{
    (void)in_sizes; (void)n_in; (void)out_size;
    const void* sup   = d_in[0];
    const void* qt    = d_in[1];
    const void* st    = d_in[2];
    const void* cls   = d_in[3];
    const void* freq  = d_in[4];
    const void* phase = d_in[5];
    const void* Wq = d_in[6];  const void* bqv = d_in[7];
    const void* Wk = d_in[8];  const void* bkv = d_in[9];
    const void* Wv = d_in[10]; const void* bvv = d_in[11];
    const void* Wo = d_in[12]; const void* bo  = d_in[13];
    const void* ln1g = d_in[14]; const void* ln1b = d_in[15];
    const void* tw = d_in[16];
    const void* W1 = d_in[17]; const void* b1 = d_in[18];
    const void* W2 = d_in[19]; const void* b2 = d_in[20];
    const void* ln2g = d_in[21]; const void* ln2b = d_in[22];
    const void* Wc = d_in[23]; const void* bc = d_in[24];
    const void* bng = d_in[25]; const void* bnb = d_in[26];

    const size_t NEEDED = 245658240;
    if (ws_size < NEEDED) {
        fill_out<<<2048, 256, 0, stream>>>((float*)d_out, 999.0f);
        return;
    }

    char* ws = (char*)d_ws;
    f16*   wt      = (f16*)(ws + 0);
    float* biasAll = (float*)(ws + 37879808);
    float* qkvb    = (float*)(ws + 44171264);
    float* prm     = (float*)(ws + 44208128);
    float* stats   = (float*)(ws + 44331584);
    int*   flag    = (int*)  (ws + 44331592);
    f16*   xb      = (f16*)(ws + 44331648);
    f16*   ob      = (f16*)(ws + 77886080);
    char*  region  = ws + 111440512;
    f16*   qb      = (f16*)(region);
    f16*   kb      = (f16*)(region + 33554432);
    f16*   vb      = (f16*)(region + 67108864);
    f16*   cb      = (f16*)(region + 100663296);
    f16*   qs      = (f16*)(region);
    f16*   xs      = (f16*)(region + 100663296);
    f16*   fbuf    = (f16*)(region);
    float* h0      = (float*)(region);

    detect_dtype<<<1, 64, 0, stream>>>(qt, flag);

    cvt_in<<<12, 256, 0, stream>>>(bo,   prm + 0,     3072,  flag);
    cvt_in<<<48, 256, 0, stream>>>(b1,   prm + 3072,  12288, flag);
    cvt_in<<<12, 256, 0, stream>>>(b2,   prm + 15360, 3072,  flag);
    cvt_in<<<1,  256, 0, stream>>>(bc,   prm + 18432, 128,   flag);
    cvt_in<<<12, 256, 0, stream>>>(ln1g, prm + 18560, 3072,  flag);
    cvt_in<<<12, 256, 0, stream>>>(ln1b, prm + 21632, 3072,  flag);
    cvt_in<<<12, 256, 0, stream>>>(ln2g, prm + 24704, 3072,  flag);
    cvt_in<<<12, 256, 0, stream>>>(ln2b, prm + 27776, 3072,  flag);
    cvt_in<<<1,  256, 0, stream>>>(bng,  prm + 30848, 8,     flag);
    cvt_in<<<1,  256, 0, stream>>>(bnb,  prm + 30856, 8,     flag);

    transpose_cvt<<<dim3(8, 8, 6),  256, 0, stream>>>(Wq, wt + 0,        512, 512,  262144, 262144, flag);
    transpose_cvt<<<dim3(8, 8, 6),  256, 0, stream>>>(Wk, wt + 1572864,  512, 512,  262144, 262144, flag);
    transpose_cvt<<<dim3(8, 8, 6),  256, 0, stream>>>(Wv, wt + 3145728,  512, 512,  262144, 262144, flag);
    transpose_cvt<<<dim3(8, 8, 6),  256, 0, stream>>>(Wo, wt + 4718592,  512, 512,  262144, 262144, flag);
    transpose_cvt<<<dim3(32, 8, 6), 256, 0, stream>>>(W1, wt + 6291456,  512, 2048, 1048576, 1048576, flag);
    transpose_cvt<<<dim3(8, 32, 6), 256, 0, stream>>>(W2, wt + 12582912, 2048, 512, 1048576, 1048576, flag);
    transpose_cvt<<<dim3(2, 8, 1),  256, 0, stream>>>(Wc, wt + 18874368, 512, 128,  0, 0, flag);
    gather_qkvb<<<36, 256, 0, stream>>>(bqv, bkv, bvv, qkvb, flag);
    build_x0<<<16384, 256, 0, stream>>>(sup, cls, xb, flag);
    build_x0s<<<512, 256, 0, stream>>>(sup, cls, xs, flag);
    bias_kernel<<<1024, 256, 0, stream>>>(qt, st, freq, phase, tw, biasAll, flag);
    hipMemsetAsync(stats, 0, 8, stream);

    for (int l = 0; l < 6; ++l) {
        if (l == 0) {
            // QKV on deduped x0: M=1024 (4 m-tiles), NZ = 2 nt * 3 z = 6
            gemm256<0><<<24, 512, 0, stream>>>(
                xs, wt, qkvb, qs,
                6, 2, 512, 512, 512, 1572864, 3072, 524288);
            attn_kernel<<<4096, 256, 0, stream>>>(
                qs, qs + 524288, qs + 1048576, biasAll, cb, 1);
        } else {
            // QKV: M=32768 (128 m-tiles), NZ = 2 nt * 3 z = 6
            gemm256<0><<<768, 512, 0, stream>>>(
                xb, wt + l * 262144, qkvb + l * 512, qb,
                6, 2, 512, 512, 512, 1572864, 3072, 16777216);
            attn_kernel<<<4096, 256, 0, stream>>>(
                qb, kb, vb, biasAll + (size_t)l * 262144, cb, 0);
        }
        // O-proj + bias + residual(xb) + LN1 -> ob  (fused)
        gemm_ln<<<256, 512, 0, stream>>>(
            cb, wt + 4718592 + l * 262144, prm + 0 + l * 512, xb,
            prm + 18560 + l * 512, prm + 21632 + l * 512, ob, 512, 512, 512);
        if (l < 5) {
            // FFN1 + gelu -> fbuf : M=32768 (128 m-tiles), NZ = 8 nt
            gemm256<2><<<1024, 512, 0, stream>>>(
                ob, wt + 6291456 + l * 1048576, prm + 3072 + l * 2048, fbuf,
                8, 8, 2048, 512, 512, 0, 0, 0);
            // FFN2 + bias + residual(ob) + LN2 -> xb  (fused)
            gemm_ln<<<256, 512, 0, stream>>>(
                fbuf, wt + 12582912 + l * 1048576, prm + 15360 + l * 512, ob,
                prm + 24704 + l * 512, prm + 27776 + l * 512, xb, 2048, 2048, 512);
        } else {
            // Last layer: only s==0 rows feed compress. M = 4096.
            // FFN1 on strided rows of ob (row r -> ob row 8r, lda=4096)
            gemm256<2><<<128, 512, 0, stream>>>(
                ob, wt + 6291456 + l * 1048576, prm + 3072 + l * 2048, fbuf,
                8, 8, 2048, 512, 4096, 0, 0, 0);
            // FFN2 + residual(ob strided) + LN2 -> cb compact [4096,512]
            gemm_ln<<<32, 512, 0, stream>>>(
                fbuf, wt + 12582912 + l * 1048576, prm + 15360 + l * 512, ob,
                prm + 24704 + l * 512, prm + 27776 + l * 512, cb, 2048, 2048, 4096);
        }
    }

    // compress on compact [4096,512] CLS rows
    gemm_bt<3><<<32, 256, 0, stream>>>(
        cb, wt + 18874368, prm + 18432, nullptr, h0,
        1, 1, 32, 1, 128, 512, 512, 0, 0, 0);
    bn_reduce<<<256, 256, 0, stream>>>(h0, stats);
    bn_apply<<<2048, 256, 0, stream>>>(h0, stats, prm + 30848, (float*)d_out);
}